// Round 1
// 447.892 us; speedup vs baseline: 1.0927x; 1.0927x over previous
//
#include <hip/hip_runtime.h>
#include <hip/hip_bf16.h>
#include <math.h>

typedef __attribute__((ext_vector_type(8))) short s8v;
typedef __attribute__((ext_vector_type(8))) _Float16 h8v;
typedef __attribute__((ext_vector_type(4))) float f4v;
typedef __attribute__((ext_vector_type(4))) double d4;
typedef __hip_bfloat16 bf16;

#define NEGF (-3.40282346638528859812e+38f)
#define DSMEM 37376  // 2*32*73*8: As+Bs, single-buffered BK=32 (R8 winner)
#define QSMEM 40960  // qk f16x2: 2 bufs x 4 mats x 64 rows x 40 shorts x 2B

enum { EPI_F32 = 0, EPI_BIAS, EPI_BRELU_BF16, EPI_BF16, EPI_FINAL };

__device__ __forceinline__ float wred_sum(float v) {
#pragma unroll
  for (int m = 1; m < 64; m <<= 1) v += __shfl_xor(v, m, 64);
  return v;
}

// ---------------------------------------------------------------------------
// f64 MFMA GEMM body (R8 winner): 64x64 tile, BK=32, single LDS buffer for
// A+B with register prefetch. A: m=lane&15,k=lane>>4; B: n=lane&15,k=lane>>4;
// D (f64 STRIDED rows): col=lane&15, row=(lane>>4)+4*reg [R4-verified].
// ---------------------------------------------------------------------------
template <int EPI>
__device__ __forceinline__ void dgemm_body(char* smem, int bx, int by, int bz,
    const double* __restrict__ A, const double* __restrict__ Bt, void* __restrict__ C,
    int K, int ldC, long sA, long sB, long sC, const double* __restrict__ bias, double scale) {
  double (*As)[73] = (double(*)[73])smem;
  double (*Bs)[73] = (double(*)[73])(smem + 32 * 73 * 8);
  const double* a = A + (long)bz * sA;
  const double* b = Bt + (long)bz * sB;
  int tid = threadIdx.x;
  int wv = tid >> 6, lane = tid & 63;
  int lm = tid >> 2;
  int lk = (tid & 3) << 3;
  long arow = (long)(bx * 64 + lm) * K + lk;
  long brow = (long)(by * 64 + lm) * K + lk;
  int fm = lane & 15, fk = lane >> 4;
  d4 acc[4] = {};
  {
    d4 a0 = *(const d4*)&a[arow], a1 = *(const d4*)&a[arow + 4];
    d4 b0 = *(const d4*)&b[brow], b1 = *(const d4*)&b[brow + 4];
#pragma unroll
    for (int j = 0; j < 4; j++) {
      As[lk + j][lm] = a0[j];
      As[lk + 4 + j][lm] = a1[j];
      Bs[lk + j][lm] = b0[j];
      Bs[lk + 4 + j][lm] = b1[j];
    }
  }
  __syncthreads();
  int nit = K >> 5;
  for (int it = 0; it < nit; it++) {
    d4 a0, a1, b0, b1;
    bool pf = (it + 1 < nit);
    if (pf) {
      long ko = (long)(it + 1) << 5;
      a0 = *(const d4*)&a[arow + ko];
      a1 = *(const d4*)&a[arow + ko + 4];
      b0 = *(const d4*)&b[brow + ko];
      b1 = *(const d4*)&b[brow + ko + 4];
    }
#pragma unroll
    for (int kk = 0; kk < 8; kk++) {
      double af = As[kk * 4 + fk][wv * 16 + fm];
#pragma unroll
      for (int nt = 0; nt < 4; nt++) {
        double bf = Bs[kk * 4 + fk][nt * 16 + fm];
        acc[nt] = __builtin_amdgcn_mfma_f64_16x16x4f64(af, bf, acc[nt], 0, 0, 0);
      }
    }
    if (pf) {
      __syncthreads();
#pragma unroll
      for (int j = 0; j < 4; j++) {
        As[lk + j][lm] = a0[j];
        As[lk + 4 + j][lm] = a1[j];
        Bs[lk + j][lm] = b0[j];
        Bs[lk + 4 + j][lm] = b1[j];
      }
      __syncthreads();
    }
  }
#pragma unroll
  for (int nt = 0; nt < 4; nt++) {
    int gn = by * 64 + nt * 16 + (lane & 15);
#pragma unroll
    for (int rg = 0; rg < 4; rg++) {
      int gm = bx * 64 + wv * 16 + (lane >> 4) + 4 * rg;
      double v = acc[nt][rg];
      if (bias) v += bias[gn];
      long ci = (long)bz * sC + (long)gm * ldC + gn;
      if (EPI == 0) ((double*)C)[ci] = v;
      else if (EPI == 1) ((double*)C)[ci] = v > 0.0 ? v : 0.0;
      else ((float*)C)[ci] = (float)(v * scale);
    }
  }
}

// f64 split-K body for skinny 2048x64x1024 (by = K-chunk id), partials to P.
__device__ __forceinline__ void dksplit_body(char* smem, int bx, int by,
    const double* __restrict__ A, const double* __restrict__ Bt, double* __restrict__ P, int K, int KC) {
  double (*As)[73] = (double(*)[73])smem;
  double (*Bs)[73] = (double(*)[73])(smem + 32 * 73 * 8);
  int tid = threadIdx.x;
  int wv = tid >> 6, lane = tid & 63;
  int lm = tid >> 2, lk = (tid & 3) << 3;
  long kbeg = (long)by * KC;
  long arow = (long)(bx * 64 + lm) * K + kbeg + lk;
  long brow = (long)lm * K + kbeg + lk;
  int fm = lane & 15, fk = lane >> 4;
  d4 acc[4] = {};
  {
    d4 a0 = *(const d4*)&A[arow], a1 = *(const d4*)&A[arow + 4];
    d4 b0 = *(const d4*)&Bt[brow], b1 = *(const d4*)&Bt[brow + 4];
#pragma unroll
    for (int j = 0; j < 4; j++) {
      As[lk + j][lm] = a0[j];
      As[lk + 4 + j][lm] = a1[j];
      Bs[lk + j][lm] = b0[j];
      Bs[lk + 4 + j][lm] = b1[j];
    }
  }
  __syncthreads();
  int nit = KC >> 5;
  for (int it = 0; it < nit; it++) {
    d4 a0, a1, b0, b1;
    bool pf = (it + 1 < nit);
    if (pf) {
      long ko = (long)(it + 1) << 5;
      a0 = *(const d4*)&A[arow + ko];
      a1 = *(const d4*)&A[arow + ko + 4];
      b0 = *(const d4*)&Bt[brow + ko];
      b1 = *(const d4*)&Bt[brow + ko + 4];
    }
#pragma unroll
    for (int kk = 0; kk < 8; kk++) {
      double af = As[kk * 4 + fk][wv * 16 + fm];
#pragma unroll
      for (int nt = 0; nt < 4; nt++) {
        double bf = Bs[kk * 4 + fk][nt * 16 + fm];
        acc[nt] = __builtin_amdgcn_mfma_f64_16x16x4f64(af, bf, acc[nt], 0, 0, 0);
      }
    }
    if (pf) {
      __syncthreads();
#pragma unroll
      for (int j = 0; j < 4; j++) {
        As[lk + j][lm] = a0[j];
        As[lk + 4 + j][lm] = a1[j];
        Bs[lk + j][lm] = b0[j];
        Bs[lk + 4 + j][lm] = b1[j];
      }
      __syncthreads();
    }
  }
  double* p = P + (long)by * 131072;
#pragma unroll
  for (int nt = 0; nt < 4; nt++) {
    int gn = nt * 16 + (lane & 15);
#pragma unroll
    for (int rg = 0; rg < 4; rg++) {
      int gm = bx * 64 + wv * 16 + (lane >> 4) + 4 * rg;
      p[(long)gm * 64 + gn] = acc[nt][rg];
    }
  }
}

// bf16 MFMA GEMM body, 64x64 tile, double-buffered (16 KB within smem).
template <int EPI>
__device__ __forceinline__ void bgemm_body(char* smem, int bx, int by, int bz,
    const bf16* __restrict__ A, const bf16* __restrict__ B, void* __restrict__ C,
    int K, int ldC, long sA, long sB, long sC,
    const float* __restrict__ bias, const void* __restrict__ aux) {
  short (*Ahs)[2048] = (short(*)[2048])smem;
  short (*Bhs)[2048] = (short(*)[2048])(smem + 2 * 2048 * 2);
  const short* ah = (const short*)A + (long)bz * sA;
  const short* bh = (const short*)B + (long)bz * sB;
  int tid = threadIdx.x;
  int wv_ = tid >> 6, lane = tid & 63;
  int lrow = tid >> 2, lcol = (tid & 3) << 3;
  int lidx = lrow * 32 + lcol;
  long abase = (long)(bx * 64 + lrow) * K + lcol;
  long bbase = (long)(by * 64 + lrow) * K + lcol;
  int frow = lane & 15, fk = (lane >> 4) << 3;
  int aoff = (wv_ * 16 + frow) * 32 + fk;
  f4v acc[4] = {};
  {
    s8v avh = *(const s8v*)&ah[abase];
    s8v bvh = *(const s8v*)&bh[bbase];
    *(s8v*)&Ahs[0][lidx] = avh;
    *(s8v*)&Bhs[0][lidx] = bvh;
  }
  __syncthreads();
  int nit = K >> 5, buf = 0;
  for (int it = 0; it < nit; it++) {
    s8v avh, bvh;
    bool pf = (it + 1 < nit);
    if (pf) {
      long ko = (long)(it + 1) << 5;
      avh = *(const s8v*)&ah[abase + ko];
      bvh = *(const s8v*)&bh[bbase + ko];
    }
    s8v afh = *(const s8v*)&Ahs[buf][aoff];
#pragma unroll
    for (int nt = 0; nt < 4; nt++) {
      s8v bfh = *(const s8v*)&Bhs[buf][(nt * 16 + frow) * 32 + fk];
      acc[nt] = __builtin_amdgcn_mfma_f32_16x16x32_bf16(afh, bfh, acc[nt], 0, 0, 0);
    }
    if (pf) {
      *(s8v*)&Ahs[buf ^ 1][lidx] = avh;
      *(s8v*)&Bhs[buf ^ 1][lidx] = bvh;
      __syncthreads();
      buf ^= 1;
    }
  }
  int rb = bx * 64 + wv_ * 16 + ((lane >> 4) << 2);
#pragma unroll
  for (int nt = 0; nt < 4; nt++) {
    int gn = by * 64 + nt * 16 + (lane & 15);
#pragma unroll
    for (int rg = 0; rg < 4; rg++) {
      int gm = rb + rg;
      float v = acc[nt][rg];
      long ci = (long)bz * sC + (long)gm * ldC + gn;
      if (EPI == EPI_F32) ((float*)C)[ci] = v;
      else if (EPI == EPI_BIAS) ((float*)C)[ci] = v + bias[gn];
      else if (EPI == EPI_BRELU_BF16) ((bf16*)C)[ci] = __float2bfloat16(fmaxf(v + bias[gn], 0.f));
      else if (EPI == EPI_BF16) ((bf16*)C)[ci] = __float2bfloat16(v);
      else if (EPI == EPI_FINAL)
        ((float*)C)[ci] = v + bias[gm] + (float)((const double*)aux)[(long)gn * 512 + gm];
    }
  }
}

// ---------------------------------------------------------------------------
// f16x2 split-GEMM body for the qk projection (R13): a*b reconstructed from
// hi/lo f16 planes (lo pre-scaled by 2^12). 4 f16 MFMAs per fragment pair
// (hh -> acc0, hl+lh -> accx @2^12, ll -> acc2 @2^24); per-product error
// ~2^-22..2^-23 ~= ref's own f32 rounding. Double-buffered, 1 barrier/iter.
// LDS row stride 40 shorts (80B): 16B-aligned b128, <=2-way bank alias.
// Fused RoPE/repack epilogue (bf16-layout D: col=lane&15,row=(lane>>4)*4+rg).
// ---------------------------------------------------------------------------
__device__ __forceinline__ void qk_f16_body(char* smem, int bx, int by,
    const _Float16* __restrict__ hhi, const _Float16* __restrict__ hlo,
    const _Float16* __restrict__ wqh, const _Float16* __restrict__ wql,
    double* __restrict__ qh, double* __restrict__ kin,
    float* __restrict__ rq, float* __restrict__ rk, const float* __restrict__ kpos) {
  short* L = (short*)smem;
  const int MS = 64 * 40;  // shorts per staged matrix
  int tid = threadIdx.x;
  int wv = tid >> 6, lane = tid & 63;
  int lrow = tid >> 2, lcol = (tid & 3) << 3;
  long abase = (long)(bx * 64 + lrow) * 512 + lcol;
  long bbase = (long)(by * 64 + lrow) * 512 + lcol;
  int frow = lane & 15, fk = (lane >> 4) << 3;
  int aoff = (wv * 16 + frow) * 40 + fk;
  int soff = lrow * 40 + lcol;
  f4v acc0[4] = {}, accx[4] = {}, acc2[4] = {};
  {
    *(h8v*)&L[0 * MS + soff] = *(const h8v*)&hhi[abase];
    *(h8v*)&L[1 * MS + soff] = *(const h8v*)&hlo[abase];
    *(h8v*)&L[2 * MS + soff] = *(const h8v*)&wqh[bbase];
    *(h8v*)&L[3 * MS + soff] = *(const h8v*)&wql[bbase];
  }
  __syncthreads();
  int buf = 0;
  for (int it = 0; it < 16; it++) {
    h8v pah, pal, pbh, pbl;
    bool pf = (it + 1 < 16);
    if (pf) {
      long ko = (long)(it + 1) << 5;
      pah = *(const h8v*)&hhi[abase + ko];
      pal = *(const h8v*)&hlo[abase + ko];
      pbh = *(const h8v*)&wqh[bbase + ko];
      pbl = *(const h8v*)&wql[bbase + ko];
    }
    int bb = buf * 4 * MS;
    h8v ah = *(const h8v*)&L[bb + aoff];
    h8v al = *(const h8v*)&L[bb + MS + aoff];
#pragma unroll
    for (int nt = 0; nt < 4; nt++) {
      int bo = bb + 2 * MS + (nt * 16 + frow) * 40 + fk;
      h8v bh = *(const h8v*)&L[bo];
      h8v bl = *(const h8v*)&L[bo + MS];
      acc0[nt] = __builtin_amdgcn_mfma_f32_16x16x32_f16(ah, bh, acc0[nt], 0, 0, 0);
      accx[nt] = __builtin_amdgcn_mfma_f32_16x16x32_f16(ah, bl, accx[nt], 0, 0, 0);
      accx[nt] = __builtin_amdgcn_mfma_f32_16x16x32_f16(al, bh, accx[nt], 0, 0, 0);
      acc2[nt] = __builtin_amdgcn_mfma_f32_16x16x32_f16(al, bl, acc2[nt], 0, 0, 0);
    }
    if (pf) {
      int b2 = (buf ^ 1) * 4 * MS;
      *(h8v*)&L[b2 + soff] = pah;
      *(h8v*)&L[b2 + MS + soff] = pal;
      *(h8v*)&L[b2 + 2 * MS + soff] = pbh;
      *(h8v*)&L[b2 + 3 * MS + soff] = pbl;
      __syncthreads();
      buf ^= 1;
    }
  }
  bool isq = by < 8;
  int h = by & 7;
  int rb = wv * 16 + ((lane >> 4) << 2);
#pragma unroll
  for (int nt = 0; nt < 4; nt++) {
    int dloc = nt * 16 + frow;
    int d2 = dloc >> 1;
    float inv = powf(10000.f, -(float)(2 * d2) / 64.f);
#pragma unroll
    for (int rg = 0; rg < 4; rg++) {
      int n = bx * 64 + rb + rg;
      float vf = acc0[nt][rg] + (accx[nt][rg] + acc2[nt][rg] * (1.f / 4096.f)) * (1.f / 4096.f);
      float ang = (float)n * inv;
      float sv = sinf(ang), cv = cosf(ang);
      float vp = __shfl_xor(vf, 1, 64);
      float rr = (dloc & 1) ? (vf * cv + vp * sv) : (vf * cv - vp * sv);
      long oi = ((long)h * 4096 + n) * 64 + dloc;
      if (isq) {
        qh[oi] = (double)vf;
        rq[oi] = rr;
      } else {
        rk[oi] = rr;
        kin[(((long)h * 256 + (n >> 4)) * 16 + (n & 15)) * 64 + dloc] =
            (double)vf + (double)kpos[(h * 16 + (n & 15)) * 64 + dloc];
      }
    }
  }
}

// Weight-cast ladder (everything NOT needed by the conv GEMM itself).
__device__ __forceinline__ void prep_elem(long i,
    const float* __restrict__ wq, const float* __restrict__ wk, const float* __restrict__ wv,
    const float* __restrict__ wst, const float* __restrict__ bst, const float* __restrict__ kc_b1,
    const float* __restrict__ kc_b2, const float* __restrict__ kc_w1, const float* __restrict__ kc_w2,
    const float* __restrict__ vc_w1, const float* __restrict__ vc_w2, const float* __restrict__ w_comb,
    const float* __restrict__ w_out, _Float16* __restrict__ wqkh, _Float16* __restrict__ wqkl,
    bf16* __restrict__ wvs,
    float* __restrict__ bias2, double* __restrict__ kb1_64, double* __restrict__ kb2_64,
    double* __restrict__ kw1_64, double* __restrict__ kw2_64, bf16* __restrict__ vw1b,
    bf16* __restrict__ vw2b, bf16* __restrict__ wcombb, bf16* __restrict__ woutb) {
  if (i < 524288) {
    int r = (int)(i >> 9), c = (int)(i & 511);
    float w = (r < 512) ? wq[i] : wk[(r - 512) * 512 + c];
    _Float16 hi = (_Float16)w;
    wqkh[i] = hi;
    wqkl[i] = (_Float16)((w - (float)hi) * 4096.f);
    return;
  }
  i -= 524288;
  if (i < 294912) {
    int r = (int)(i >> 9), c = (int)(i & 511);
    float v = 0.f;
    if (r < 512) v = wv[i];
    else if (r < 536) v = wst[(r - 512) * 512 + c];
    wvs[i] = __float2bfloat16(v);
    if (i < 576) bias2[i] = (i >= 512 && i < 536) ? bst[i - 512] : 0.f;
    return;
  }
  i -= 294912;
  if (i < 1088) {
    if (i < 1024) kb1_64[i] = (double)kc_b1[i];
    else kb2_64[i - 1024] = (double)kc_b2[i - 1024];
    return;
  }
  i -= 1088;
  if (i < 1048576) { kw1_64[i] = (double)kc_w1[i]; return; }
  i -= 1048576;
  if (i < 65536) { kw2_64[i] = (double)kc_w2[i]; return; }
  i -= 65536;
  if (i < 1048576) { vw1b[i] = __float2bfloat16(vc_w1[i]); return; }
  i -= 1048576;
  if (i < 65536) { vw2b[i] = __float2bfloat16(vc_w2[i]); return; }
  i -= 65536;
  if (i < 262144) { wcombb[i] = __float2bfloat16(w_comb[i]); return; }
  i -= 262144;
  if (i < 262144) woutb[i] = __float2bfloat16(w_out[i]);
}
#define PREP_TOTAL 3572800l

// ---- standalone kernels ----
template <int EPI>
__global__ __launch_bounds__(256) void dgemm_bt(
    const double* __restrict__ A, const double* __restrict__ Bt, void* __restrict__ C,
    int K, int ldC, long sA, long sB, long sC, const double* __restrict__ bias, double scale) {
  __shared__ char smem[DSMEM];
  dgemm_body<EPI>(smem, blockIdx.x, blockIdx.y, blockIdx.z, A, Bt, C, K, ldC, sA, sB, sC, bias, scale);
}

template <int EPI>
__global__ __launch_bounds__(256) void gemm_bt(
    const bf16* __restrict__ A, const bf16* __restrict__ B, void* __restrict__ C,
    int K, int ldC, long sA, long sB, long sC,
    const float* __restrict__ bias, const void* __restrict__ aux) {
  __shared__ char smem[4 * 2048 * 2];
  bgemm_body<EPI>(smem, blockIdx.x, blockIdx.y, blockIdx.z, A, B, C, K, ldC, sA, sB, sC, bias, aux);
}

// conv f64 GEMM (y<8) + weight-prep casts (y>=8) in one dispatch.
__global__ __launch_bounds__(256) void k_conv_prep(
    const double* __restrict__ xt64, const double* __restrict__ win64, double* __restrict__ xs64,
    const double* __restrict__ b_in64,
    const float* __restrict__ wq, const float* __restrict__ wk, const float* __restrict__ wv,
    const float* __restrict__ wst, const float* __restrict__ bst, const float* __restrict__ kc_b1,
    const float* __restrict__ kc_b2, const float* __restrict__ kc_w1, const float* __restrict__ kc_w2,
    const float* __restrict__ vc_w1, const float* __restrict__ vc_w2, const float* __restrict__ w_comb,
    const float* __restrict__ w_out, _Float16* __restrict__ wqkh, _Float16* __restrict__ wqkl,
    bf16* __restrict__ wvs,
    float* __restrict__ bias2, double* __restrict__ kb1_64, double* __restrict__ kb2_64,
    double* __restrict__ kw1_64, double* __restrict__ kw2_64, bf16* __restrict__ vw1b,
    bf16* __restrict__ vw2b, bf16* __restrict__ wcombb, bf16* __restrict__ woutb) {
  __shared__ char smem[DSMEM];
  if (blockIdx.y < 8) {
    dgemm_body<0>(smem, blockIdx.x, blockIdx.y, 0, xt64, win64, xs64, 512, 512, 0, 0, 0, b_in64, 1.0);
  } else {
    long base = (((long)(blockIdx.y - 8) * 64 + blockIdx.x) * 256) + threadIdx.x;
    for (long i = base; i < PREP_TOTAL; i += 16l * 64 * 256)
      prep_elem(i, wq, wk, wv, wst, bst, kc_b1, kc_b2, kc_w1, kc_w2, vc_w1, vc_w2, w_comb, w_out,
                wqkh, wqkl, wvs, bias2, kb1_64, kb2_64, kw1_64, kw2_64, vw1b, vw2b, wcombb, woutb);
  }
}

// ---------------------------------------------------------------------------
// qk f16x2 split-GEMM (by<16) with FUSED repack epilogue (R13). q-blocks
// (by<8): qh64 + roped rq; k-blocks (by 8..15): roped rk + kin64 (+k_pos).
// RoPE partner via shfl_xor. bf16 T2 GEMM at by>=16.
// ---------------------------------------------------------------------------
__global__ __launch_bounds__(256) void k_fused_qk_t2(
    const _Float16* __restrict__ hhi, const _Float16* __restrict__ hlo,
    const _Float16* __restrict__ wqkh, const _Float16* __restrict__ wqkl,
    double* __restrict__ qh, double* __restrict__ kin,
    float* __restrict__ rq, float* __restrict__ rk, const float* __restrict__ kpos,
    const bf16* __restrict__ hbf, const bf16* __restrict__ wvs, float* __restrict__ T2,
    const float* __restrict__ bias2) {
  __shared__ char smem[QSMEM];
  if (blockIdx.y >= 16) {
    bgemm_body<EPI_BIAS>(smem, blockIdx.x, blockIdx.y - 16, 0, hbf, wvs, T2, 512, 576, 0, 0, 0, bias2,
                         nullptr);
    return;
  }
  qk_f16_body(smem, blockIdx.x, blockIdx.y, hhi, hlo, wqkh, wqkl, qh, kin, rq, rk, kpos);
}

// slim v-repack: T2 v-part -> vvb (f32 head-major) + vin (bf16 + v_pos).
__global__ void k_repackV(const float* __restrict__ T2, const float* __restrict__ vpos,
                          float* __restrict__ vvv, bf16* __restrict__ vin) {
  int e = blockIdx.x * 256 + threadIdx.x;  // 8*4096*64
  int d = e & 63, n = (e >> 6) & 4095, h = e >> 18;
  float v0 = T2[(long)n * 576 + h * 64 + d];
  vvv[((long)h * 4096 + n) * 64 + d] = v0;
  vin[(((long)h * 256 + (n >> 4)) * 16 + (n & 15)) * 64 + d] =
      __float2bfloat16(v0 + vpos[(h * 16 + (n & 15)) * 64 + d]);
}

__global__ __launch_bounds__(256) void k_fused_mlp1(
    const double* __restrict__ kin, const double* __restrict__ kw1, double* __restrict__ hidk,
    const double* __restrict__ kb1, const bf16* __restrict__ vin, const bf16* __restrict__ vw1,
    bf16* __restrict__ hidv, const float* __restrict__ vb1) {
  __shared__ char smem[DSMEM];
  if (blockIdx.y < 16)
    dgemm_body<1>(smem, blockIdx.x, blockIdx.y, 0, kin, kw1, hidk, 1024, 1024, 0, 0, 0, kb1, 1.0);
  else
    bgemm_body<EPI_BRELU_BF16>(smem, blockIdx.x, blockIdx.y - 16, 0, vin, vw1, hidv, 1024, 1024, 0, 0, 0,
                               vb1, nullptr);
}

__global__ __launch_bounds__(256) void k_fused_mlp2(
    const double* __restrict__ hidk, const double* __restrict__ kw2, double* __restrict__ kpart,
    const bf16* __restrict__ hidv, const bf16* __restrict__ vw2, float* __restrict__ cvc,
    const float* __restrict__ vb2) {
  __shared__ char smem[DSMEM];
  if (blockIdx.y < 8)
    dksplit_body(smem, blockIdx.x, blockIdx.y, hidk, kw2, kpart, 1024, 128);
  else
    bgemm_body<EPI_BIAS>(smem, blockIdx.x, 0, 0, hidv, vw2, cvc, 1024, 64, 0, 0, 0, vb2, nullptr);
}

// x (512,4096) f32 -> xt (4096,512) f64; y==16 slab casts win64/b_in64.
__global__ void k_transpose64(const float* __restrict__ x, double* __restrict__ xt,
                              const float* __restrict__ w_in, const float* __restrict__ b_in,
                              double* __restrict__ win64, double* __restrict__ b_in64) {
  if (blockIdx.y == 16) {
    int tid = threadIdx.y * 32 + threadIdx.x;
    long base = (long)blockIdx.x * 256 + tid;
    for (long i = base; i < 262656; i += 128l * 256) {
      if (i < 262144) win64[i] = (double)w_in[i];
      else b_in64[i - 262144] = (double)b_in[i - 262144];
    }
    return;
  }
  __shared__ float t[32][33];
  int n0 = blockIdx.x * 32, c0 = blockIdx.y * 32;
  int tx = threadIdx.x, ty = threadIdx.y;
#pragma unroll
  for (int r = ty; r < 32; r += 8) t[r][tx] = x[(long)(c0 + r) * 4096 + n0 + tx];
  __syncthreads();
#pragma unroll
  for (int r = ty; r < 32; r += 8) xt[(long)(n0 + r) * 512 + c0 + tx] = (double)t[tx][r];
}

// rmsnorm (f64 math) -> h split into f16 hi/lo planes (lo pre-scaled 2^12)
// for the qk GEMM, + bf16 h for the T2 GEMM. (h64 dropped: qk no longer f64.)
__global__ __launch_bounds__(256) void k_rmsnorm64(const double* __restrict__ xs, const float* __restrict__ g,
                                                   _Float16* __restrict__ hhi, _Float16* __restrict__ hlo,
                                                   bf16* __restrict__ hbf) {
  int n = blockIdx.x, t = threadIdx.x;
  const double* row = xs + (long)n * 512;
  double a = row[t], b = row[t + 256];
  double ss = a * a + b * b;
#pragma unroll
  for (int m = 1; m < 64; m <<= 1) ss += __shfl_xor(ss, m, 64);
  __shared__ double red[4];
  if ((t & 63) == 0) red[t >> 6] = ss;
  __syncthreads();
  double tot = red[0] + red[1] + red[2] + red[3];
  double r = 1.0 / sqrt(tot / 512.0 + 1e-6);
  double h0 = a * r * (double)g[t], h1 = b * r * (double)g[t + 256];
  long o = (long)n * 512 + t;
  float f0 = (float)h0, f1 = (float)h1;
  _Float16 a0 = (_Float16)f0, a1 = (_Float16)f1;
  hhi[o] = a0;
  hhi[o + 256] = a1;
  hlo[o] = (_Float16)((f0 - (float)a0) * 4096.f);
  hlo[o + 256] = (_Float16)((f1 - (float)a1) * 4096.f);
  hbf[o] = __float2bfloat16(f0);
  hbf[o + 256] = __float2bfloat16(f1);
}

// split-K partials (8x 2048x64) + cvc + mem rows -> ckb64 (8,320,64 f64), cvtb (8,64,288 bf16).
__global__ void k_repackB64(const double* __restrict__ kpart, const float* __restrict__ cvc,
                            const float* __restrict__ mem_k, const float* __restrict__ mem_v,
                            const double* __restrict__ kb2, double* __restrict__ ckb,
                            bf16* __restrict__ cvtb) {
  int g = blockIdx.x * 256 + threadIdx.x;
  if (g < 8 * 320 * 64) {
    int d = g & 63, j = (g >> 6) % 320, h = g / (320 * 64);
    double v = 0.0;
    if (j == 0) v = (double)mem_k[h * 64 + d];
    else if (j < 257) {
      long ri = ((long)h * 256 + (j - 1)) * 64 + d;
      double s = 0.0;
#pragma unroll
      for (int p = 0; p < 8; p++) s += kpart[(long)p * 131072 + ri];
      v = s + kb2[d];
    }
    ckb[g] = v;
  }
  if (g < 8 * 64 * 288) {
    int j = g % 288, d = (g / 288) & 63, h = g / (288 * 64);
    float v = 0.f;
    if (j == 0) v = mem_v[h * 64 + d];
    else if (j < 257) v = cvc[((long)h * 256 + (j - 1)) * 64 + d];
    cvtb[g] = __float2bfloat16(v);
  }
}

// Per (h,i) row: compressed softmax -> probs (bf16), and exact top-k block selection.
__global__ __launch_bounds__(256) void k_selsm(const float* __restrict__ csim, bf16* __restrict__ pb,
                                               int4* __restrict__ selb) {
  int r = blockIdx.x * 4 + (threadIdx.x >> 6);
  int lane = threadIdx.x & 63;
  int i = r & 4095;
  const float* row = csim + (long)r * 320;
  int nv = i / 16 + 1;
  float s[5], e[5];
  float mx = -INFINITY;
#pragma unroll
  for (int t = 0; t < 5; t++) {
    int j = lane + 64 * t;
    float v = (j < nv) ? row[j] : -INFINITY;
    s[t] = v;
    mx = fmaxf(mx, v);
  }
#pragma unroll
  for (int m = 1; m < 64; m <<= 1) mx = fmaxf(mx, __shfl_xor(mx, m, 64));
  float sum = 0.f;
#pragma unroll
  for (int t = 0; t < 5; t++) {
    int j = lane + 64 * t;
    e[t] = (j < nv) ? __expf(s[t] - mx) : 0.f;
    sum += e[t];
  }
  sum = wred_sum(sum);
  float rinv = 1.f / sum;
  bf16* prow = pb + (long)r * 288;
#pragma unroll
  for (int t = 0; t < 5; t++) {
    int j = lane + 64 * t;
    if (j < 288) prow[j] = __float2bfloat16((j < nv) ? e[t] * rinv : 0.f);
  }
  int nvb = i >> 1;
  int nmv = (nvb + 7) >> 3;
  float vm[4];
  float bestv = -INFINITY;
  int bestm = 0x7fffffff;
#pragma unroll
  for (int t = 0; t < 4; t++) {
    int m = lane + 64 * t;
    float v = -INFINITY;
    if (m < nmv) v = (m + 1 < nv) ? row[m + 1] : NEGF;
    vm[t] = v;
    if (v > bestv) { bestv = v; bestm = m; }
  }
#pragma unroll
  for (int mk = 1; mk < 64; mk <<= 1) {
    float ov = __shfl_xor(bestv, mk, 64);
    int om = __shfl_xor(bestm, mk, 64);
    if (ov > bestv || (ov == bestv && om < bestm)) { bestv = ov; bestm = om; }
  }
  int m0 = bestm;
  int cnt0 = min(8, nvb - 8 * m0);
  float rv = -INFINITY;
  int rm = 0x7fffffff;
#pragma unroll
  for (int t = 0; t < 4; t++) {
    int m = lane + 64 * t;
    if (m != m0 && vm[t] > rv) { rv = vm[t]; rm = m; }
  }
#pragma unroll
  for (int mk = 1; mk < 64; mk <<= 1) {
    float ov = __shfl_xor(rv, mk, 64);
    int om = __shfl_xor(rm, mk, 64);
    if (ov > rv || (ov == rv && om < rm)) { rv = ov; rm = om; }
  }
  float Ml = fmaxf(-1000.f, bestv);
  float z = 0.f;
#pragma unroll
  for (int t = 0; t < 4; t++) {
    int m = lane + 64 * t;
    if (m < nmv) z += (float)min(8, nvb - 8 * m) * expf(vm[t] - Ml);
  }
  z = wred_sum(z) + expf(-1000.f - Ml);
  int fb0 = 0, fb1 = 0, mk0 = 0, mk1 = 0;
  if (nmv > 0) {
    float sv0 = expf(bestv - Ml) / z;
    fb0 = 8 * m0;
    mk0 = sv0 > 1e-10f;
    if (cnt0 >= 2) { fb1 = fb0 + 1; mk1 = mk0; }
    else if (nmv > 1) {
      float sv1 = expf(rv - Ml) / z;
      fb1 = 8 * rm;
      mk1 = sv1 > 1e-10f;
    }
  }
  if (lane == 0) selb[r] = make_int4(fb0, fb1, mk0, mk1);
}

// Per (h,i): fine attention (selected + diag) + sliding window + gated combine.
// (R12: restored standalone — 32768 waves of TLP hide the scattered gathers;
// fusing this into the pv GEMM block (R11) cut TLP 16x and cost +38µs.)
__global__ __launch_bounds__(256) void k_fineslide(const float* __restrict__ rq, const float* __restrict__ rk,
                                                   const float* __restrict__ vv, const float* __restrict__ co,
                                                   const int4* __restrict__ selb, const float* __restrict__ T2,
                                                   bf16* __restrict__ comb) {
  int r = blockIdx.x * 4 + (threadIdx.x >> 6);
  int d = threadIdx.x & 63;
  int h = r >> 12, i = r & 4095;
  long hb = (long)h * 4096 * 64;
  float qd = rq[hb + (long)i * 64 + d];
  int4 s4 = selb[r];
  int dg = i >> 1;
  int tok[6] = {2 * s4.x, 2 * s4.x + 1, 2 * s4.y, 2 * s4.y + 1, 2 * dg, 2 * dg + 1};
  int ok6[6] = {s4.z, s4.z, s4.w, s4.w, 1, (i & 1)};
  float sim[6], val[6];
#pragma unroll
  for (int j = 0; j < 6; j++) {
    float kd = rk[hb + (long)tok[j] * 64 + d];
    val[j] = vv[hb + (long)tok[j] * 64 + d];
    float p = wred_sum(qd * kd);
    sim[j] = ok6[j] ? p * 0.125f : NEGF;
  }
  float mx = sim[0];
#pragma unroll
  for (int j = 1; j < 6; j++) mx = fmaxf(mx, sim[j]);
  float den = 0.f, fo = 0.f;
#pragma unroll
  for (int j = 0; j < 6; j++) {
    float e_ = __expf(sim[j] - mx);
    den += e_;
    fo += e_ * val[j];
  }
  fo /= den;
  float ssim[9], sval[9];
#pragma unroll
  for (int t = 0; t < 9; t++) {
    int tk = i - 8 + t;
    int okt = tk >= 0;
    int tc = okt ? tk : 0;
    float kd = rk[hb + (long)tc * 64 + d];
    sval[t] = okt ? vv[hb + (long)tc * 64 + d] : 0.f;
    float p = wred_sum(qd * kd);
    ssim[t] = okt ? p * 0.125f : NEGF;
  }
  float mx2 = ssim[8];
#pragma unroll
  for (int t = 0; t < 8; t++) mx2 = fmaxf(mx2, ssim[t]);
  float den2 = 0.f, so = 0.f;
#pragma unroll
  for (int t = 0; t < 9; t++) {
    float e_ = __expf(ssim[t] - mx2);
    den2 += e_;
    so += e_ * sval[t];
  }
  so /= den2;
  const float* gb = T2 + (long)i * 576 + 512 + h * 3;
  float g0 = 1.f / (1.f + __expf(-gb[0]));
  float g1 = 1.f / (1.f + __expf(-gb[1]));
  float g2 = 1.f / (1.f + __expf(-gb[2]));
  float cd = co[hb + (long)i * 64 + d];
  comb[(long)i * 512 + h * 64 + d] = __float2bfloat16(g0 * cd + g1 * fo + g2 * so);
}

extern "C" void kernel_launch(void* const* d_in, const int* in_sizes, int n_in, void* d_out, int out_size,
                              void* d_ws, size_t ws_size, hipStream_t stream) {
  (void)in_sizes; (void)n_in; (void)out_size; (void)ws_size;
  const float* x = (const float*)d_in[0];
  const float* w_in = (const float*)d_in[1];
  const float* b_in = (const float*)d_in[2];
  const float* g_norm = (const float*)d_in[3];
  const float* wq = (const float*)d_in[4];
  const float* wk = (const float*)d_in[5];
  const float* wv = (const float*)d_in[6];
  const float* k_pos = (const float*)d_in[7];
  const float* v_pos = (const float*)d_in[8];
  const float* mem_k = (const float*)d_in[9];
  const float* mem_v = (const float*)d_in[10];
  const float* kc_w1 = (const float*)d_in[11];
  const float* kc_b1 = (const float*)d_in[12];
  const float* kc_w2 = (const float*)d_in[13];
  const float* kc_b2 = (const float*)d_in[14];
  const float* vc_w1 = (const float*)d_in[15];
  const float* vc_b1 = (const float*)d_in[16];
  const float* vc_w2 = (const float*)d_in[17];
  const float* vc_b2 = (const float*)d_in[18];
  const float* w_strat = (const float*)d_in[19];
  const float* b_strat = (const float*)d_in[20];
  const float* w_comb = (const float*)d_in[21];
  const float* w_out = (const float*)d_in[22];
  const float* b_out = (const float*)d_in[23];

  char* wsp = (char*)d_ws;
  size_t off = 0;
  auto alloc = [&](size_t b) -> void* {
    void* p = wsp + off;
    off += (b + 255) & ~(size_t)255;
    return p;
  };
  double* xs64 = (double*)alloc(4096l * 512 * 8);
  _Float16* hhi = (_Float16*)alloc(4096l * 512 * 2);
  _Float16* hlo = (_Float16*)alloc(4096l * 512 * 2);
  bf16* hbf = (bf16*)alloc(4096l * 512 * 2);
  double* win64 = (double*)alloc(512l * 512 * 8);
  _Float16* wqkh = (_Float16*)alloc(1024l * 512 * 2);
  _Float16* wqkl = (_Float16*)alloc(1024l * 512 * 2);
  bf16* wvs = (bf16*)alloc(576l * 512 * 2);
  float* bias2 = (float*)alloc(576 * 4);
  double* b_in64 = (double*)alloc(512 * 8);
  double* kb1_64 = (double*)alloc(1024 * 8);
  double* kb2_64 = (double*)alloc(64 * 8);
  float* T2 = (float*)alloc(4096l * 576 * 4);
  float* csim = (float*)alloc(8l * 4096 * 320 * 4);
  double* qh64 = (double*)alloc(8l * 4096 * 64 * 8);
  float* rq = (float*)alloc(8l * 4096 * 64 * 4);
  float* rk = (float*)alloc(8l * 4096 * 64 * 4);
  float* vvb = (float*)alloc(8l * 4096 * 64 * 4);
  double* xt64 = (double*)alloc(4096l * 512 * 8);  // reused later as hidk64
  double* hidk64 = xt64;
  char* kinpb = (char*)alloc(2048l * 1024 * 8 + 2048l * 1024 * 2);  // kin64+vin, later pb
  double* kin64 = (double*)kinpb;
  bf16* vinb = (bf16*)(kinpb + 2048l * 1024 * 8);
  bf16* pb = (bf16*)kinpb;
  double* kw1_64 = (double*)alloc(1024l * 1024 * 8);
  double* kw2_64 = (double*)alloc(64l * 1024 * 8);
  bf16* vw1b = (bf16*)alloc(1024l * 1024 * 2);
  bf16* vw2b = (bf16*)alloc(64l * 1024 * 2);
  bf16* hidv = (bf16*)alloc(2048l * 1024 * 2);
  float* cvc = (float*)alloc(2048l * 64 * 4);
  double* ckb64 = (double*)alloc(8l * 320 * 64 * 8);
  bf16* cvtb = (bf16*)alloc(8l * 64 * 288 * 2);
  int4* selb = (int4*)alloc(32768l * 16);
  float* co = (float*)alloc(8l * 4096 * 64 * 4);
  bf16* comb = (bf16*)alloc(4096l * 512 * 2);
  bf16* zb = (bf16*)alloc(4096l * 512 * 2);
  bf16* wcombb = (bf16*)alloc(512l * 512 * 2);
  bf16* woutb = (bf16*)alloc(512l * 512 * 2);
  double* kpart = (double*)alloc(8l * 2048 * 64 * 8);  // split-K partials

  // ---- transpose + conv-weight cast ----
  k_transpose64<<<dim3(128, 17), dim3(32, 8), 0, stream>>>(x, xt64, w_in, b_in, win64, b_in64);
  // ---- conv (f64) + all remaining weight prep in one dispatch ----
  k_conv_prep<<<dim3(64, 24), 256, 0, stream>>>(xt64, win64, xs64, b_in64, wq, wk, wv, w_strat, b_strat,
                                                kc_b1, kc_b2, kc_w1, kc_w2, vc_w1, vc_w2, w_comb, w_out,
                                                wqkh, wqkl, wvs, bias2, kb1_64, kb2_64, kw1_64, kw2_64,
                                                vw1b, vw2b, wcombb, woutb);
  k_rmsnorm64<<<4096, 256, 0, stream>>>(xs64, g_norm, hhi, hlo, hbf);
  // ---- qk f16x2 GEMM with fused repack epilogue (+ T2 bf16 GEMM) ----
  k_fused_qk_t2<<<dim3(64, 25, 1), 256, 0, stream>>>(hhi, hlo, wqkh, wqkl, qh64, kin64, rq, rk, k_pos,
                                                     hbf, wvs, T2, bias2);
  k_repackV<<<8192, 256, 0, stream>>>(T2, v_pos, vvb, vinb);
  k_fused_mlp1<<<dim3(32, 32, 1), 256, 0, stream>>>(kin64, kw1_64, hidk64, kb1_64, vinb, vw1b, hidv, vc_b1);
  k_fused_mlp2<<<dim3(32, 9, 1), 256, 0, stream>>>(hidk64, kw2_64, kpart, hidv, vw2b, cvc, vc_b2);
  k_repackB64<<<640, 256, 0, stream>>>(kpart, cvc, mem_k, mem_v, kb2_64, ckb64, cvtb);
  dgemm_bt<2><<<dim3(64, 5, 8), 256, 0, stream>>>(qh64, ckb64, csim, 64, 320, 4096l * 64, 320l * 64,
                                                  4096l * 320, nullptr, 0.125);
  // ---- selection + attention combine (standalone fineslide, full TLP) ----
  k_selsm<<<8192, 256, 0, stream>>>(csim, pb, selb);
  gemm_bt<EPI_F32><<<dim3(64, 1, 8), 256, 0, stream>>>(pb, cvtb, co, 288, 64, 4096l * 288, 64l * 288,
                                                       4096l * 64, nullptr, nullptr);
  k_fineslide<<<8192, 256, 0, stream>>>(rq, rk, vvb, co, selb, T2, comb);
  // ---- output mixing ----
  gemm_bt<EPI_BF16><<<dim3(64, 8, 1), 256, 0, stream>>>(comb, wcombb, zb, 512, 512, 0, 0, 0, nullptr, nullptr);
  gemm_bt<EPI_FINAL><<<dim3(8, 64, 1), 256, 0, stream>>>(woutb, zb, d_out, 512, 4096, 0, 0, 0, b_out, xs64);
}

// Round 2
// 425.189 us; speedup vs baseline: 1.1510x; 1.0534x over previous
//
#include <hip/hip_runtime.h>
#include <hip/hip_bf16.h>
#include <math.h>

typedef __attribute__((ext_vector_type(8))) short s8v;
typedef __attribute__((ext_vector_type(8))) _Float16 h8v;
typedef __attribute__((ext_vector_type(4))) float f4v;
typedef __attribute__((ext_vector_type(4))) double d4;
typedef __hip_bfloat16 bf16;

#define NEGF (-3.40282346638528859812e+38f)
#define DSMEM 37376  // 2*32*73*8: As+Bs, single-buffered BK=32 (R8 winner)
#define QSMEM 40960  // f16x2: 2 bufs x 4 mats x 64 rows x 40 shorts x 2B

enum { EPI_F32 = 0, EPI_BIAS, EPI_BRELU_BF16, EPI_BF16, EPI_FINAL };

__device__ __forceinline__ float wred_sum(float v) {
#pragma unroll
  for (int m = 1; m < 64; m <<= 1) v += __shfl_xor(v, m, 64);
  return v;
}

// ---------------------------------------------------------------------------
// f64 MFMA GEMM body (R8 winner): 64x64 tile, BK=32, single LDS buffer for
// A+B with register prefetch. A: m=lane&15,k=lane>>4; B: n=lane&15,k=lane>>4;
// D (f64 STRIDED rows): col=lane&15, row=(lane>>4)+4*reg [R4-verified].
// ---------------------------------------------------------------------------
template <int EPI>
__device__ __forceinline__ void dgemm_body(char* smem, int bx, int by, int bz,
    const double* __restrict__ A, const double* __restrict__ Bt, void* __restrict__ C,
    int K, int ldC, long sA, long sB, long sC, const double* __restrict__ bias, double scale) {
  double (*As)[73] = (double(*)[73])smem;
  double (*Bs)[73] = (double(*)[73])(smem + 32 * 73 * 8);
  const double* a = A + (long)bz * sA;
  const double* b = Bt + (long)bz * sB;
  int tid = threadIdx.x;
  int wv = tid >> 6, lane = tid & 63;
  int lm = tid >> 2;
  int lk = (tid & 3) << 3;
  long arow = (long)(bx * 64 + lm) * K + lk;
  long brow = (long)(by * 64 + lm) * K + lk;
  int fm = lane & 15, fk = lane >> 4;
  d4 acc[4] = {};
  {
    d4 a0 = *(const d4*)&a[arow], a1 = *(const d4*)&a[arow + 4];
    d4 b0 = *(const d4*)&b[brow], b1 = *(const d4*)&b[brow + 4];
#pragma unroll
    for (int j = 0; j < 4; j++) {
      As[lk + j][lm] = a0[j];
      As[lk + 4 + j][lm] = a1[j];
      Bs[lk + j][lm] = b0[j];
      Bs[lk + 4 + j][lm] = b1[j];
    }
  }
  __syncthreads();
  int nit = K >> 5;
  for (int it = 0; it < nit; it++) {
    d4 a0, a1, b0, b1;
    bool pf = (it + 1 < nit);
    if (pf) {
      long ko = (long)(it + 1) << 5;
      a0 = *(const d4*)&a[arow + ko];
      a1 = *(const d4*)&a[arow + ko + 4];
      b0 = *(const d4*)&b[brow + ko];
      b1 = *(const d4*)&b[brow + ko + 4];
    }
#pragma unroll
    for (int kk = 0; kk < 8; kk++) {
      double af = As[kk * 4 + fk][wv * 16 + fm];
#pragma unroll
      for (int nt = 0; nt < 4; nt++) {
        double bf = Bs[kk * 4 + fk][nt * 16 + fm];
        acc[nt] = __builtin_amdgcn_mfma_f64_16x16x4f64(af, bf, acc[nt], 0, 0, 0);
      }
    }
    if (pf) {
      __syncthreads();
#pragma unroll
      for (int j = 0; j < 4; j++) {
        As[lk + j][lm] = a0[j];
        As[lk + 4 + j][lm] = a1[j];
        Bs[lk + j][lm] = b0[j];
        Bs[lk + 4 + j][lm] = b1[j];
      }
      __syncthreads();
    }
  }
#pragma unroll
  for (int nt = 0; nt < 4; nt++) {
    int gn = by * 64 + nt * 16 + (lane & 15);
#pragma unroll
    for (int rg = 0; rg < 4; rg++) {
      int gm = bx * 64 + wv * 16 + (lane >> 4) + 4 * rg;
      double v = acc[nt][rg];
      if (bias) v += bias[gn];
      long ci = (long)bz * sC + (long)gm * ldC + gn;
      if (EPI == 0) ((double*)C)[ci] = v;
      else if (EPI == 1) ((double*)C)[ci] = v > 0.0 ? v : 0.0;
      else ((float*)C)[ci] = (float)(v * scale);
    }
  }
}

// bf16 MFMA GEMM body, 64x64 tile, double-buffered (16 KB within smem).
template <int EPI>
__device__ __forceinline__ void bgemm_body(char* smem, int bx, int by, int bz,
    const bf16* __restrict__ A, const bf16* __restrict__ B, void* __restrict__ C,
    int K, int ldC, long sA, long sB, long sC,
    const float* __restrict__ bias, const void* __restrict__ aux) {
  short (*Ahs)[2048] = (short(*)[2048])smem;
  short (*Bhs)[2048] = (short(*)[2048])(smem + 2 * 2048 * 2);
  const short* ah = (const short*)A + (long)bz * sA;
  const short* bh = (const short*)B + (long)bz * sB;
  int tid = threadIdx.x;
  int wv_ = tid >> 6, lane = tid & 63;
  int lrow = tid >> 2, lcol = (tid & 3) << 3;
  int lidx = lrow * 32 + lcol;
  long abase = (long)(bx * 64 + lrow) * K + lcol;
  long bbase = (long)(by * 64 + lrow) * K + lcol;
  int frow = lane & 15, fk = (lane >> 4) << 3;
  int aoff = (wv_ * 16 + frow) * 32 + fk;
  f4v acc[4] = {};
  {
    s8v avh = *(const s8v*)&ah[abase];
    s8v bvh = *(const s8v*)&bh[bbase];
    *(s8v*)&Ahs[0][lidx] = avh;
    *(s8v*)&Bhs[0][lidx] = bvh;
  }
  __syncthreads();
  int nit = K >> 5, buf = 0;
  for (int it = 0; it < nit; it++) {
    s8v avh, bvh;
    bool pf = (it + 1 < nit);
    if (pf) {
      long ko = (long)(it + 1) << 5;
      avh = *(const s8v*)&ah[abase + ko];
      bvh = *(const s8v*)&bh[bbase + ko];
    }
    s8v afh = *(const s8v*)&Ahs[buf][aoff];
#pragma unroll
    for (int nt = 0; nt < 4; nt++) {
      s8v bfh = *(const s8v*)&Bhs[buf][(nt * 16 + frow) * 32 + fk];
      acc[nt] = __builtin_amdgcn_mfma_f32_16x16x32_bf16(afh, bfh, acc[nt], 0, 0, 0);
    }
    if (pf) {
      *(s8v*)&Ahs[buf ^ 1][lidx] = avh;
      *(s8v*)&Bhs[buf ^ 1][lidx] = bvh;
      __syncthreads();
      buf ^= 1;
    }
  }
  int rb = bx * 64 + wv_ * 16 + ((lane >> 4) << 2);
#pragma unroll
  for (int nt = 0; nt < 4; nt++) {
    int gn = by * 64 + nt * 16 + (lane & 15);
#pragma unroll
    for (int rg = 0; rg < 4; rg++) {
      int gm = rb + rg;
      float v = acc[nt][rg];
      long ci = (long)bz * sC + (long)gm * ldC + gn;
      if (EPI == EPI_F32) ((float*)C)[ci] = v;
      else if (EPI == EPI_BIAS) ((float*)C)[ci] = v + bias[gn];
      else if (EPI == EPI_BRELU_BF16) ((bf16*)C)[ci] = __float2bfloat16(fmaxf(v + bias[gn], 0.f));
      else if (EPI == EPI_BF16) ((bf16*)C)[ci] = __float2bfloat16(v);
      else if (EPI == EPI_FINAL)
        ((float*)C)[ci] = v + bias[gm] + (float)((const double*)aux)[(long)gn * 512 + gm];
    }
  }
}

// ---------------------------------------------------------------------------
// f16x2 split-GEMM machinery (R13/R14): a*b reconstructed from hi/lo f16
// planes (lo pre-scaled by 2^12). 4 f16 MFMAs per fragment pair (hh -> acc0,
// hl+lh -> accx @2^-12, ll -> acc2 @2^-24); per-product error ~2^-22..2^-23
// ~= the reference's own f32 rounding. Double-buffered, 1 barrier/iter.
// LDS row stride 40 shorts (80B): 16B-aligned b128, <=2-way bank alias.
// ---------------------------------------------------------------------------

#define HX_DECL                                                     \
  short* L = (short*)smem;                                          \
  const int MS = 64 * 40;                                           \
  int tid = threadIdx.x;                                            \
  int wv = tid >> 6, lane = tid & 63;                               \
  int lrow = tid >> 2, lcol = (tid & 3) << 3;                       \
  int frow = lane & 15, fk = (lane >> 4) << 3;                      \
  int aoff = (wv * 16 + frow) * 40 + fk;                            \
  int soff = lrow * 40 + lcol;                                      \
  f4v acc0[4] = {}, accx[4] = {}, acc2[4] = {};

#define HX_STAGE0                                                   \
  {                                                                 \
    *(h8v*)&L[0 * MS + soff] = *(const h8v*)&Ah[abase];             \
    *(h8v*)&L[1 * MS + soff] = *(const h8v*)&Al[abase];             \
    *(h8v*)&L[2 * MS + soff] = *(const h8v*)&Bh[bbase];             \
    *(h8v*)&L[3 * MS + soff] = *(const h8v*)&Bl[bbase];             \
  }                                                                 \
  __syncthreads();

#define HX_LOOP(NIT)                                                \
  int buf = 0;                                                      \
  for (int it = 0; it < (NIT); it++) {                              \
    h8v pah, pal, pbh, pbl;                                         \
    bool pf = (it + 1 < (NIT));                                     \
    if (pf) {                                                       \
      long ko = (long)(it + 1) << 5;                                \
      pah = *(const h8v*)&Ah[abase + ko];                           \
      pal = *(const h8v*)&Al[abase + ko];                           \
      pbh = *(const h8v*)&Bh[bbase + ko];                           \
      pbl = *(const h8v*)&Bl[bbase + ko];                           \
    }                                                               \
    int bb = buf * 4 * MS;                                          \
    h8v ah = *(const h8v*)&L[bb + aoff];                            \
    h8v al = *(const h8v*)&L[bb + MS + aoff];                       \
    _Pragma("unroll") for (int nt = 0; nt < 4; nt++) {              \
      int bo = bb + 2 * MS + (nt * 16 + frow) * 40 + fk;            \
      h8v bh = *(const h8v*)&L[bo];                                 \
      h8v bl = *(const h8v*)&L[bo + MS];                            \
      acc0[nt] = __builtin_amdgcn_mfma_f32_16x16x32_f16(ah, bh, acc0[nt], 0, 0, 0); \
      accx[nt] = __builtin_amdgcn_mfma_f32_16x16x32_f16(ah, bl, accx[nt], 0, 0, 0); \
      accx[nt] = __builtin_amdgcn_mfma_f32_16x16x32_f16(al, bh, accx[nt], 0, 0, 0); \
      acc2[nt] = __builtin_amdgcn_mfma_f32_16x16x32_f16(al, bl, acc2[nt], 0, 0, 0); \
    }                                                               \
    if (pf) {                                                       \
      int b2 = (buf ^ 1) * 4 * MS;                                  \
      *(h8v*)&L[b2 + soff] = pah;                                   \
      *(h8v*)&L[b2 + MS + soff] = pal;                              \
      *(h8v*)&L[b2 + 2 * MS + soff] = pbh;                          \
      *(h8v*)&L[b2 + 3 * MS + soff] = pbl;                          \
      __syncthreads();                                              \
      buf ^= 1;                                                     \
    }                                                               \
  }

#define HX_COMBINE(nt, rg) \
  (acc0[nt][rg] + (accx[nt][rg] + acc2[nt][rg] * (1.f / 4096.f)) * (1.f / 4096.f))

// qk projection body with fused RoPE/repack epilogue.
// D layout (16x16x32 family): col=lane&15, row=(lane>>4)*4+rg.
__device__ __forceinline__ void qk_f16_body(char* smem, int bx, int by,
    const _Float16* __restrict__ Ah, const _Float16* __restrict__ Al,
    const _Float16* __restrict__ Bh, const _Float16* __restrict__ Bl,
    double* __restrict__ qh, _Float16* __restrict__ kinh, _Float16* __restrict__ kinl,
    float* __restrict__ rq, float* __restrict__ rk, const float* __restrict__ kpos) {
  HX_DECL
  long abase = (long)(bx * 64 + lrow) * 512 + lcol;
  long bbase = (long)(by * 64 + lrow) * 512 + lcol;
  HX_STAGE0
  HX_LOOP(16)
  bool isq = by < 8;
  int h = by & 7;
  int rb = wv * 16 + ((lane >> 4) << 2);
#pragma unroll
  for (int nt = 0; nt < 4; nt++) {
    int dloc = nt * 16 + frow;
    int d2 = dloc >> 1;
    float inv = powf(10000.f, -(float)(2 * d2) / 64.f);
#pragma unroll
    for (int rg = 0; rg < 4; rg++) {
      int n = bx * 64 + rb + rg;
      float vf = HX_COMBINE(nt, rg);
      float ang = (float)n * inv;
      float sv = sinf(ang), cv = cosf(ang);
      float vp = __shfl_xor(vf, 1, 64);
      float rr = (dloc & 1) ? (vf * cv + vp * sv) : (vf * cv - vp * sv);
      long oi = ((long)h * 4096 + n) * 64 + dloc;
      if (isq) {
        qh[oi] = (double)vf;
        rq[oi] = rr;
      } else {
        rk[oi] = rr;
        float kv = vf + kpos[(h * 16 + (n & 15)) * 64 + dloc];
        _Float16 khi = (_Float16)kv;
        long ki = (((long)h * 256 + (n >> 4)) * 16 + (n & 15)) * 64 + dloc;
        kinh[ki] = khi;
        kinl[ki] = (_Float16)((kv - (float)khi) * 4096.f);
      }
    }
  }
}

// K-MLP1: hid = relu(kin @ kw1^T + b1), output re-split into hi/lo planes.
__device__ __forceinline__ void hx_mlp1_body(char* smem, int bx, int by,
    const _Float16* __restrict__ Ah, const _Float16* __restrict__ Al,
    const _Float16* __restrict__ Bh, const _Float16* __restrict__ Bl,
    _Float16* __restrict__ Ch, _Float16* __restrict__ Cl, const float* __restrict__ bias) {
  HX_DECL
  long abase = (long)(bx * 64 + lrow) * 1024 + lcol;
  long bbase = (long)(by * 64 + lrow) * 1024 + lcol;
  HX_STAGE0
  HX_LOOP(32)
  int rb = bx * 64 + wv * 16 + ((lane >> 4) << 2);
#pragma unroll
  for (int nt = 0; nt < 4; nt++) {
    int gn = by * 64 + nt * 16 + frow;
#pragma unroll
    for (int rg = 0; rg < 4; rg++) {
      int gm = rb + rg;
      float v = fmaxf(HX_COMBINE(nt, rg) + bias[gn], 0.f);
      _Float16 hi = (_Float16)v;
      long ci = (long)gm * 1024 + gn;
      Ch[ci] = hi;
      Cl[ci] = (_Float16)((v - (float)hi) * 4096.f);
    }
  }
}

// K-MLP2 split-K (by = K-chunk of 128): f32 partials to P[by].
__device__ __forceinline__ void hx_ksplit_body(char* smem, int bx, int by,
    const _Float16* __restrict__ Ah, const _Float16* __restrict__ Al,
    const _Float16* __restrict__ Bh, const _Float16* __restrict__ Bl,
    float* __restrict__ P) {
  HX_DECL
  long kbeg = (long)by << 7;
  long abase = (long)(bx * 64 + lrow) * 1024 + kbeg + lcol;
  long bbase = (long)lrow * 1024 + kbeg + lcol;
  HX_STAGE0
  HX_LOOP(4)
  float* p = P + (long)by * 131072;
  int rb = bx * 64 + wv * 16 + ((lane >> 4) << 2);
#pragma unroll
  for (int nt = 0; nt < 4; nt++) {
    int gn = nt * 16 + frow;
#pragma unroll
    for (int rg = 0; rg < 4; rg++) {
      int gm = rb + rg;
      p[(long)gm * 64 + gn] = HX_COMBINE(nt, rg);
    }
  }
}

// Weight-cast ladder (everything NOT needed by the conv GEMM itself).
__device__ __forceinline__ void prep_elem(long i,
    const float* __restrict__ wq, const float* __restrict__ wk, const float* __restrict__ wv,
    const float* __restrict__ wst, const float* __restrict__ bst,
    const float* __restrict__ kc_b2, const float* __restrict__ kc_w1, const float* __restrict__ kc_w2,
    const float* __restrict__ vc_w1, const float* __restrict__ vc_w2, const float* __restrict__ w_comb,
    const float* __restrict__ w_out, _Float16* __restrict__ wqkh, _Float16* __restrict__ wqkl,
    bf16* __restrict__ wvs,
    float* __restrict__ bias2, double* __restrict__ kb2_64,
    _Float16* __restrict__ kw1h, _Float16* __restrict__ kw1l,
    _Float16* __restrict__ kw2h, _Float16* __restrict__ kw2l, bf16* __restrict__ vw1b,
    bf16* __restrict__ vw2b, bf16* __restrict__ wcombb, bf16* __restrict__ woutb) {
  if (i < 524288) {
    int r = (int)(i >> 9), c = (int)(i & 511);
    float w = (r < 512) ? wq[i] : wk[(r - 512) * 512 + c];
    _Float16 hi = (_Float16)w;
    wqkh[i] = hi;
    wqkl[i] = (_Float16)((w - (float)hi) * 4096.f);
    return;
  }
  i -= 524288;
  if (i < 294912) {
    int r = (int)(i >> 9), c = (int)(i & 511);
    float v = 0.f;
    if (r < 512) v = wv[i];
    else if (r < 536) v = wst[(r - 512) * 512 + c];
    wvs[i] = __float2bfloat16(v);
    if (i < 576) bias2[i] = (i >= 512 && i < 536) ? bst[i - 512] : 0.f;
    return;
  }
  i -= 294912;
  if (i < 1088) {
    if (i >= 1024) kb2_64[i - 1024] = (double)kc_b2[i - 1024];
    return;
  }
  i -= 1088;
  if (i < 1048576) {
    float w = kc_w1[i];
    _Float16 hi = (_Float16)w;
    kw1h[i] = hi;
    kw1l[i] = (_Float16)((w - (float)hi) * 4096.f);
    return;
  }
  i -= 1048576;
  if (i < 65536) {
    float w = kc_w2[i];
    _Float16 hi = (_Float16)w;
    kw2h[i] = hi;
    kw2l[i] = (_Float16)((w - (float)hi) * 4096.f);
    return;
  }
  i -= 65536;
  if (i < 1048576) { vw1b[i] = __float2bfloat16(vc_w1[i]); return; }
  i -= 1048576;
  if (i < 65536) { vw2b[i] = __float2bfloat16(vc_w2[i]); return; }
  i -= 65536;
  if (i < 262144) { wcombb[i] = __float2bfloat16(w_comb[i]); return; }
  i -= 262144;
  if (i < 262144) woutb[i] = __float2bfloat16(w_out[i]);
}
#define PREP_TOTAL 3572800l

// ---- standalone kernels ----
template <int EPI>
__global__ __launch_bounds__(256) void dgemm_bt(
    const double* __restrict__ A, const double* __restrict__ Bt, void* __restrict__ C,
    int K, int ldC, long sA, long sB, long sC, const double* __restrict__ bias, double scale) {
  __shared__ char smem[DSMEM];
  dgemm_body<EPI>(smem, blockIdx.x, blockIdx.y, blockIdx.z, A, Bt, C, K, ldC, sA, sB, sC, bias, scale);
}

template <int EPI>
__global__ __launch_bounds__(256) void gemm_bt(
    const bf16* __restrict__ A, const bf16* __restrict__ B, void* __restrict__ C,
    int K, int ldC, long sA, long sB, long sC,
    const float* __restrict__ bias, const void* __restrict__ aux) {
  __shared__ char smem[4 * 2048 * 2];
  bgemm_body<EPI>(smem, blockIdx.x, blockIdx.y, blockIdx.z, A, B, C, K, ldC, sA, sB, sC, bias, aux);
}

// conv f64 GEMM (y<8) + weight-prep casts (y>=8) in one dispatch.
__global__ __launch_bounds__(256) void k_conv_prep(
    const double* __restrict__ xt64, const double* __restrict__ win64, double* __restrict__ xs64,
    const double* __restrict__ b_in64,
    const float* __restrict__ wq, const float* __restrict__ wk, const float* __restrict__ wv,
    const float* __restrict__ wst, const float* __restrict__ bst,
    const float* __restrict__ kc_b2, const float* __restrict__ kc_w1, const float* __restrict__ kc_w2,
    const float* __restrict__ vc_w1, const float* __restrict__ vc_w2, const float* __restrict__ w_comb,
    const float* __restrict__ w_out, _Float16* __restrict__ wqkh, _Float16* __restrict__ wqkl,
    bf16* __restrict__ wvs,
    float* __restrict__ bias2, double* __restrict__ kb2_64,
    _Float16* __restrict__ kw1h, _Float16* __restrict__ kw1l,
    _Float16* __restrict__ kw2h, _Float16* __restrict__ kw2l, bf16* __restrict__ vw1b,
    bf16* __restrict__ vw2b, bf16* __restrict__ wcombb, bf16* __restrict__ woutb) {
  __shared__ char smem[DSMEM];
  if (blockIdx.y < 8) {
    dgemm_body<0>(smem, blockIdx.x, blockIdx.y, 0, xt64, win64, xs64, 512, 512, 0, 0, 0, b_in64, 1.0);
  } else {
    long base = (((long)(blockIdx.y - 8) * 64 + blockIdx.x) * 256) + threadIdx.x;
    for (long i = base; i < PREP_TOTAL; i += 16l * 64 * 256)
      prep_elem(i, wq, wk, wv, wst, bst, kc_b2, kc_w1, kc_w2, vc_w1, vc_w2, w_comb, w_out,
                wqkh, wqkl, wvs, bias2, kb2_64, kw1h, kw1l, kw2h, kw2l, vw1b, vw2b, wcombb, woutb);
  }
}

// ---------------------------------------------------------------------------
// qk f16x2 split-GEMM (by<16) with FUSED repack epilogue. q-blocks (by<8):
// qh64 + roped rq; k-blocks (by 8..15): roped rk + kin hi/lo (+k_pos).
// RoPE partner via shfl_xor. bf16 T2 GEMM at by>=16.
// ---------------------------------------------------------------------------
__global__ __launch_bounds__(256) void k_fused_qk_t2(
    const _Float16* __restrict__ hhi, const _Float16* __restrict__ hlo,
    const _Float16* __restrict__ wqkh, const _Float16* __restrict__ wqkl,
    double* __restrict__ qh, _Float16* __restrict__ kinh, _Float16* __restrict__ kinl,
    float* __restrict__ rq, float* __restrict__ rk, const float* __restrict__ kpos,
    const bf16* __restrict__ hbf, const bf16* __restrict__ wvs, float* __restrict__ T2,
    const float* __restrict__ bias2) {
  __shared__ char smem[QSMEM];
  if (blockIdx.y >= 16) {
    bgemm_body<EPI_BIAS>(smem, blockIdx.x, blockIdx.y - 16, 0, hbf, wvs, T2, 512, 576, 0, 0, 0, bias2,
                         nullptr);
    return;
  }
  qk_f16_body(smem, blockIdx.x, blockIdx.y, hhi, hlo, wqkh, wqkl, qh, kinh, kinl, rq, rk, kpos);
}

// slim v-repack: T2 v-part -> vvb (f32 head-major) + vin (bf16 + v_pos).
__global__ void k_repackV(const float* __restrict__ T2, const float* __restrict__ vpos,
                          float* __restrict__ vvv, bf16* __restrict__ vin) {
  int e = blockIdx.x * 256 + threadIdx.x;  // 8*4096*64
  int d = e & 63, n = (e >> 6) & 4095, h = e >> 18;
  float v0 = T2[(long)n * 576 + h * 64 + d];
  vvv[((long)h * 4096 + n) * 64 + d] = v0;
  vin[(((long)h * 256 + (n >> 4)) * 16 + (n & 15)) * 64 + d] =
      __float2bfloat16(v0 + vpos[(h * 16 + (n & 15)) * 64 + d]);
}

// K-MLP1 f16x2 (y<16) + V-MLP1 bf16 (y>=16).
__global__ __launch_bounds__(256) void k_fused_mlp1(
    const _Float16* __restrict__ kinh, const _Float16* __restrict__ kinl,
    const _Float16* __restrict__ kw1h, const _Float16* __restrict__ kw1l,
    _Float16* __restrict__ hidh, _Float16* __restrict__ hidl, const float* __restrict__ kb1,
    const bf16* __restrict__ vin, const bf16* __restrict__ vw1,
    bf16* __restrict__ hidv, const float* __restrict__ vb1) {
  __shared__ char smem[QSMEM];
  if (blockIdx.y < 16)
    hx_mlp1_body(smem, blockIdx.x, blockIdx.y, kinh, kinl, kw1h, kw1l, hidh, hidl, kb1);
  else
    bgemm_body<EPI_BRELU_BF16>(smem, blockIdx.x, blockIdx.y - 16, 0, vin, vw1, hidv, 1024, 1024, 0, 0, 0,
                               vb1, nullptr);
}

// K-MLP2 f16x2 split-K (y<8) + V-MLP2 bf16 (y==8).
__global__ __launch_bounds__(256) void k_fused_mlp2(
    const _Float16* __restrict__ hidh, const _Float16* __restrict__ hidl,
    const _Float16* __restrict__ kw2h, const _Float16* __restrict__ kw2l, float* __restrict__ kpart,
    const bf16* __restrict__ hidv, const bf16* __restrict__ vw2, float* __restrict__ cvc,
    const float* __restrict__ vb2) {
  __shared__ char smem[QSMEM];
  if (blockIdx.y < 8)
    hx_ksplit_body(smem, blockIdx.x, blockIdx.y, hidh, hidl, kw2h, kw2l, kpart);
  else
    bgemm_body<EPI_BIAS>(smem, blockIdx.x, 0, 0, hidv, vw2, cvc, 1024, 64, 0, 0, 0, vb2, nullptr);
}

// x (512,4096) f32 -> xt (4096,512) f64; y==16 slab casts win64/b_in64.
__global__ void k_transpose64(const float* __restrict__ x, double* __restrict__ xt,
                              const float* __restrict__ w_in, const float* __restrict__ b_in,
                              double* __restrict__ win64, double* __restrict__ b_in64) {
  if (blockIdx.y == 16) {
    int tid = threadIdx.y * 32 + threadIdx.x;
    long base = (long)blockIdx.x * 256 + tid;
    for (long i = base; i < 262656; i += 128l * 256) {
      if (i < 262144) win64[i] = (double)w_in[i];
      else b_in64[i - 262144] = (double)b_in[i - 262144];
    }
    return;
  }
  __shared__ float t[32][33];
  int n0 = blockIdx.x * 32, c0 = blockIdx.y * 32;
  int tx = threadIdx.x, ty = threadIdx.y;
#pragma unroll
  for (int r = ty; r < 32; r += 8) t[r][tx] = x[(long)(c0 + r) * 4096 + n0 + tx];
  __syncthreads();
#pragma unroll
  for (int r = ty; r < 32; r += 8) xt[(long)(n0 + r) * 512 + c0 + tx] = (double)t[tx][r];
}

// rmsnorm (f64 math) -> h split into f16 hi/lo planes (lo pre-scaled 2^12)
// for the qk GEMM, + bf16 h for the T2 GEMM.
__global__ __launch_bounds__(256) void k_rmsnorm64(const double* __restrict__ xs, const float* __restrict__ g,
                                                   _Float16* __restrict__ hhi, _Float16* __restrict__ hlo,
                                                   bf16* __restrict__ hbf) {
  int n = blockIdx.x, t = threadIdx.x;
  const double* row = xs + (long)n * 512;
  double a = row[t], b = row[t + 256];
  double ss = a * a + b * b;
#pragma unroll
  for (int m = 1; m < 64; m <<= 1) ss += __shfl_xor(ss, m, 64);
  __shared__ double red[4];
  if ((t & 63) == 0) red[t >> 6] = ss;
  __syncthreads();
  double tot = red[0] + red[1] + red[2] + red[3];
  double r = 1.0 / sqrt(tot / 512.0 + 1e-6);
  double h0 = a * r * (double)g[t], h1 = b * r * (double)g[t + 256];
  long o = (long)n * 512 + t;
  float f0 = (float)h0, f1 = (float)h1;
  _Float16 a0 = (_Float16)f0, a1 = (_Float16)f1;
  hhi[o] = a0;
  hhi[o + 256] = a1;
  hlo[o] = (_Float16)((f0 - (float)a0) * 4096.f);
  hlo[o + 256] = (_Float16)((f1 - (float)a1) * 4096.f);
  hbf[o] = __float2bfloat16(f0);
  hbf[o + 256] = __float2bfloat16(f1);
}

// split-K f32 partials (8x 2048x64) + cvc + mem rows -> ckb64 (8,320,64 f64), cvtb (8,64,288 bf16).
__global__ void k_repackB64(const float* __restrict__ kpart, const float* __restrict__ cvc,
                            const float* __restrict__ mem_k, const float* __restrict__ mem_v,
                            const double* __restrict__ kb2, double* __restrict__ ckb,
                            bf16* __restrict__ cvtb) {
  int g = blockIdx.x * 256 + threadIdx.x;
  if (g < 8 * 320 * 64) {
    int d = g & 63, j = (g >> 6) % 320, h = g / (320 * 64);
    double v = 0.0;
    if (j == 0) v = (double)mem_k[h * 64 + d];
    else if (j < 257) {
      long ri = ((long)h * 256 + (j - 1)) * 64 + d;
      double s = 0.0;
#pragma unroll
      for (int p = 0; p < 8; p++) s += (double)kpart[(long)p * 131072 + ri];
      v = s + kb2[d];
    }
    ckb[g] = v;
  }
  if (g < 8 * 64 * 288) {
    int j = g % 288, d = (g / 288) & 63, h = g / (288 * 64);
    float v = 0.f;
    if (j == 0) v = mem_v[h * 64 + d];
    else if (j < 257) v = cvc[((long)h * 256 + (j - 1)) * 64 + d];
    cvtb[g] = __float2bfloat16(v);
  }
}

// Per (h,i) row: compressed softmax -> probs (bf16), and exact top-k block selection.
__global__ __launch_bounds__(256) void k_selsm(const float* __restrict__ csim, bf16* __restrict__ pb,
                                               int4* __restrict__ selb) {
  int r = blockIdx.x * 4 + (threadIdx.x >> 6);
  int lane = threadIdx.x & 63;
  int i = r & 4095;
  const float* row = csim + (long)r * 320;
  int nv = i / 16 + 1;
  float s[5], e[5];
  float mx = -INFINITY;
#pragma unroll
  for (int t = 0; t < 5; t++) {
    int j = lane + 64 * t;
    float v = (j < nv) ? row[j] : -INFINITY;
    s[t] = v;
    mx = fmaxf(mx, v);
  }
#pragma unroll
  for (int m = 1; m < 64; m <<= 1) mx = fmaxf(mx, __shfl_xor(mx, m, 64));
  float sum = 0.f;
#pragma unroll
  for (int t = 0; t < 5; t++) {
    int j = lane + 64 * t;
    e[t] = (j < nv) ? __expf(s[t] - mx) : 0.f;
    sum += e[t];
  }
  sum = wred_sum(sum);
  float rinv = 1.f / sum;
  bf16* prow = pb + (long)r * 288;
#pragma unroll
  for (int t = 0; t < 5; t++) {
    int j = lane + 64 * t;
    if (j < 288) prow[j] = __float2bfloat16((j < nv) ? e[t] * rinv : 0.f);
  }
  int nvb = i >> 1;
  int nmv = (nvb + 7) >> 3;
  float vm[4];
  float bestv = -INFINITY;
  int bestm = 0x7fffffff;
#pragma unroll
  for (int t = 0; t < 4; t++) {
    int m = lane + 64 * t;
    float v = -INFINITY;
    if (m < nmv) v = (m + 1 < nv) ? row[m + 1] : NEGF;
    vm[t] = v;
    if (v > bestv) { bestv = v; bestm = m; }
  }
#pragma unroll
  for (int mk = 1; mk < 64; mk <<= 1) {
    float ov = __shfl_xor(bestv, mk, 64);
    int om = __shfl_xor(bestm, mk, 64);
    if (ov > bestv || (ov == bestv && om < bestm)) { bestv = ov; bestm = om; }
  }
  int m0 = bestm;
  int cnt0 = min(8, nvb - 8 * m0);
  float rv = -INFINITY;
  int rm = 0x7fffffff;
#pragma unroll
  for (int t = 0; t < 4; t++) {
    int m = lane + 64 * t;
    if (m != m0 && vm[t] > rv) { rv = vm[t]; rm = m; }
  }
#pragma unroll
  for (int mk = 1; mk < 64; mk <<= 1) {
    float ov = __shfl_xor(rv, mk, 64);
    int om = __shfl_xor(rm, mk, 64);
    if (ov > rv || (ov == rv && om < rm)) { rv = ov; rm = om; }
  }
  float Ml = fmaxf(-1000.f, bestv);
  float z = 0.f;
#pragma unroll
  for (int t = 0; t < 4; t++) {
    int m = lane + 64 * t;
    if (m < nmv) z += (float)min(8, nvb - 8 * m) * expf(vm[t] - Ml);
  }
  z = wred_sum(z) + expf(-1000.f - Ml);
  int fb0 = 0, fb1 = 0, mk0 = 0, mk1 = 0;
  if (nmv > 0) {
    float sv0 = expf(bestv - Ml) / z;
    fb0 = 8 * m0;
    mk0 = sv0 > 1e-10f;
    if (cnt0 >= 2) { fb1 = fb0 + 1; mk1 = mk0; }
    else if (nmv > 1) {
      float sv1 = expf(rv - Ml) / z;
      fb1 = 8 * rm;
      mk1 = sv1 > 1e-10f;
    }
  }
  if (lane == 0) selb[r] = make_int4(fb0, fb1, mk0, mk1);
}

// Per (h,i): fine attention (selected + diag) + sliding window + gated combine.
__global__ __launch_bounds__(256) void k_fineslide(const float* __restrict__ rq, const float* __restrict__ rk,
                                                   const float* __restrict__ vv, const float* __restrict__ co,
                                                   const int4* __restrict__ selb, const float* __restrict__ T2,
                                                   bf16* __restrict__ comb) {
  int r = blockIdx.x * 4 + (threadIdx.x >> 6);
  int d = threadIdx.x & 63;
  int h = r >> 12, i = r & 4095;
  long hb = (long)h * 4096 * 64;
  float qd = rq[hb + (long)i * 64 + d];
  int4 s4 = selb[r];
  int dg = i >> 1;
  int tok[6] = {2 * s4.x, 2 * s4.x + 1, 2 * s4.y, 2 * s4.y + 1, 2 * dg, 2 * dg + 1};
  int ok6[6] = {s4.z, s4.z, s4.w, s4.w, 1, (i & 1)};
  float sim[6], val[6];
#pragma unroll
  for (int j = 0; j < 6; j++) {
    float kd = rk[hb + (long)tok[j] * 64 + d];
    val[j] = vv[hb + (long)tok[j] * 64 + d];
    float p = wred_sum(qd * kd);
    sim[j] = ok6[j] ? p * 0.125f : NEGF;
  }
  float mx = sim[0];
#pragma unroll
  for (int j = 1; j < 6; j++) mx = fmaxf(mx, sim[j]);
  float den = 0.f, fo = 0.f;
#pragma unroll
  for (int j = 0; j < 6; j++) {
    float e_ = __expf(sim[j] - mx);
    den += e_;
    fo += e_ * val[j];
  }
  fo /= den;
  float ssim[9], sval[9];
#pragma unroll
  for (int t = 0; t < 9; t++) {
    int tk = i - 8 + t;
    int okt = tk >= 0;
    int tc = okt ? tk : 0;
    float kd = rk[hb + (long)tc * 64 + d];
    sval[t] = okt ? vv[hb + (long)tc * 64 + d] : 0.f;
    float p = wred_sum(qd * kd);
    ssim[t] = okt ? p * 0.125f : NEGF;
  }
  float mx2 = ssim[8];
#pragma unroll
  for (int t = 0; t < 8; t++) mx2 = fmaxf(mx2, ssim[t]);
  float den2 = 0.f, so = 0.f;
#pragma unroll
  for (int t = 0; t < 9; t++) {
    float e_ = __expf(ssim[t] - mx2);
    den2 += e_;
    so += e_ * sval[t];
  }
  so /= den2;
  const float* gb = T2 + (long)i * 576 + 512 + h * 3;
  float g0 = 1.f / (1.f + __expf(-gb[0]));
  float g1 = 1.f / (1.f + __expf(-gb[1]));
  float g2 = 1.f / (1.f + __expf(-gb[2]));
  float cd = co[hb + (long)i * 64 + d];
  comb[(long)i * 512 + h * 64 + d] = __float2bfloat16(g0 * cd + g1 * fo + g2 * so);
}

extern "C" void kernel_launch(void* const* d_in, const int* in_sizes, int n_in, void* d_out, int out_size,
                              void* d_ws, size_t ws_size, hipStream_t stream) {
  (void)in_sizes; (void)n_in; (void)out_size; (void)ws_size;
  const float* x = (const float*)d_in[0];
  const float* w_in = (const float*)d_in[1];
  const float* b_in = (const float*)d_in[2];
  const float* g_norm = (const float*)d_in[3];
  const float* wq = (const float*)d_in[4];
  const float* wk = (const float*)d_in[5];
  const float* wv = (const float*)d_in[6];
  const float* k_pos = (const float*)d_in[7];
  const float* v_pos = (const float*)d_in[8];
  const float* mem_k = (const float*)d_in[9];
  const float* mem_v = (const float*)d_in[10];
  const float* kc_w1 = (const float*)d_in[11];
  const float* kc_b1 = (const float*)d_in[12];
  const float* kc_w2 = (const float*)d_in[13];
  const float* kc_b2 = (const float*)d_in[14];
  const float* vc_w1 = (const float*)d_in[15];
  const float* vc_b1 = (const float*)d_in[16];
  const float* vc_w2 = (const float*)d_in[17];
  const float* vc_b2 = (const float*)d_in[18];
  const float* w_strat = (const float*)d_in[19];
  const float* b_strat = (const float*)d_in[20];
  const float* w_comb = (const float*)d_in[21];
  const float* w_out = (const float*)d_in[22];
  const float* b_out = (const float*)d_in[23];

  char* wsp = (char*)d_ws;
  size_t off = 0;
  auto alloc = [&](size_t b) -> void* {
    void* p = wsp + off;
    off += (b + 255) & ~(size_t)255;
    return p;
  };
  double* xs64 = (double*)alloc(4096l * 512 * 8);
  _Float16* hhi = (_Float16*)alloc(4096l * 512 * 2);
  _Float16* hlo = (_Float16*)alloc(4096l * 512 * 2);
  bf16* hbf = (bf16*)alloc(4096l * 512 * 2);
  double* win64 = (double*)alloc(512l * 512 * 8);
  _Float16* wqkh = (_Float16*)alloc(1024l * 512 * 2);
  _Float16* wqkl = (_Float16*)alloc(1024l * 512 * 2);
  bf16* wvs = (bf16*)alloc(576l * 512 * 2);
  float* bias2 = (float*)alloc(576 * 4);
  double* b_in64 = (double*)alloc(512 * 8);
  double* kb2_64 = (double*)alloc(64 * 8);
  float* T2 = (float*)alloc(4096l * 576 * 4);
  float* csim = (float*)alloc(8l * 4096 * 320 * 4);
  double* qh64 = (double*)alloc(8l * 4096 * 64 * 8);
  float* rq = (float*)alloc(8l * 4096 * 64 * 4);
  float* rk = (float*)alloc(8l * 4096 * 64 * 4);
  float* vvb = (float*)alloc(8l * 4096 * 64 * 4);
  double* xt64 = (double*)alloc(4096l * 512 * 8);  // reused later as hid hi/lo
  _Float16* hidh = (_Float16*)xt64;
  _Float16* hidl = hidh + 2048l * 1024;
  char* kinpb = (char*)alloc(2048l * 1024 * 8 + 2048l * 1024 * 2);  // kin hi/lo + vin, later pb
  _Float16* kinh = (_Float16*)kinpb;
  _Float16* kinl = kinh + 2048l * 1024;
  bf16* vinb = (bf16*)(kinpb + 2l * 2048 * 1024 * 2);
  bf16* pb = (bf16*)kinpb;
  _Float16* kw1h = (_Float16*)alloc(1024l * 1024 * 2);
  _Float16* kw1l = (_Float16*)alloc(1024l * 1024 * 2);
  _Float16* kw2h = (_Float16*)alloc(64l * 1024 * 2);
  _Float16* kw2l = (_Float16*)alloc(64l * 1024 * 2);
  bf16* vw1b = (bf16*)alloc(1024l * 1024 * 2);
  bf16* vw2b = (bf16*)alloc(64l * 1024 * 2);
  bf16* hidv = (bf16*)alloc(2048l * 1024 * 2);
  float* cvc = (float*)alloc(2048l * 64 * 4);
  double* ckb64 = (double*)alloc(8l * 320 * 64 * 8);
  bf16* cvtb = (bf16*)alloc(8l * 64 * 288 * 2);
  int4* selb = (int4*)alloc(32768l * 16);
  float* co = (float*)alloc(8l * 4096 * 64 * 4);
  bf16* comb = (bf16*)alloc(4096l * 512 * 2);
  bf16* zb = (bf16*)alloc(4096l * 512 * 2);
  bf16* wcombb = (bf16*)alloc(512l * 512 * 2);
  bf16* woutb = (bf16*)alloc(512l * 512 * 2);
  float* kpart = (float*)alloc(8l * 2048 * 64 * 4);  // split-K f32 partials

  // ---- transpose + conv-weight cast ----
  k_transpose64<<<dim3(128, 17), dim3(32, 8), 0, stream>>>(x, xt64, w_in, b_in, win64, b_in64);
  // ---- conv (f64) + all remaining weight prep in one dispatch ----
  k_conv_prep<<<dim3(64, 24), 256, 0, stream>>>(xt64, win64, xs64, b_in64, wq, wk, wv, w_strat, b_strat,
                                                kc_b2, kc_w1, kc_w2, vc_w1, vc_w2, w_comb, w_out,
                                                wqkh, wqkl, wvs, bias2, kb2_64, kw1h, kw1l, kw2h, kw2l,
                                                vw1b, vw2b, wcombb, woutb);
  k_rmsnorm64<<<4096, 256, 0, stream>>>(xs64, g_norm, hhi, hlo, hbf);
  // ---- qk f16x2 GEMM with fused repack epilogue (+ T2 bf16 GEMM) ----
  k_fused_qk_t2<<<dim3(64, 25, 1), 256, 0, stream>>>(hhi, hlo, wqkh, wqkl, qh64, kinh, kinl, rq, rk, k_pos,
                                                     hbf, wvs, T2, bias2);
  k_repackV<<<8192, 256, 0, stream>>>(T2, v_pos, vvb, vinb);
  k_fused_mlp1<<<dim3(32, 32, 1), 256, 0, stream>>>(kinh, kinl, kw1h, kw1l, hidh, hidl, kc_b1, vinb, vw1b,
                                                    hidv, vc_b1);
  k_fused_mlp2<<<dim3(32, 9, 1), 256, 0, stream>>>(hidh, hidl, kw2h, kw2l, kpart, hidv, vw2b, cvc, vc_b2);
  k_repackB64<<<640, 256, 0, stream>>>(kpart, cvc, mem_k, mem_v, kb2_64, ckb64, cvtb);
  dgemm_bt<2><<<dim3(64, 5, 8), 256, 0, stream>>>(qh64, ckb64, csim, 64, 320, 4096l * 64, 320l * 64,
                                                  4096l * 320, nullptr, 0.125);
  // ---- selection + attention combine (standalone fineslide, full TLP) ----
  k_selsm<<<8192, 256, 0, stream>>>(csim, pb, selb);
  gemm_bt<EPI_F32><<<dim3(64, 1, 8), 256, 0, stream>>>(pb, cvtb, co, 288, 64, 4096l * 288, 64l * 288,
                                                       4096l * 64, nullptr, nullptr);
  k_fineslide<<<8192, 256, 0, stream>>>(rq, rk, vvb, co, selb, T2, comb);
  // ---- output mixing ----
  gemm_bt<EPI_BF16><<<dim3(64, 8, 1), 256, 0, stream>>>(comb, wcombb, zb, 512, 512, 0, 0, 0, nullptr, nullptr);
  gemm_bt<EPI_FINAL><<<dim3(8, 64, 1), 256, 0, stream>>>(woutb, zb, d_out, 512, 4096, 0, 0, 0, b_out, xs64);
}

// Round 3
// 331.472 us; speedup vs baseline: 1.4765x; 1.2827x over previous
//
#include <hip/hip_runtime.h>
#include <hip/hip_bf16.h>
#include <math.h>

typedef __attribute__((ext_vector_type(8))) short s8v;
typedef __attribute__((ext_vector_type(8))) _Float16 h8v;
typedef __attribute__((ext_vector_type(4))) float f4v;
typedef __hip_bfloat16 bf16;

#define NEGF (-3.40282346638528859812e+38f)
#define QSMEM 20480  // f16x2 single-buffer: 4 mats x 64 rows x 40 shorts x 2B

enum { EPI_F32 = 0, EPI_BIAS, EPI_BRELU_BF16, EPI_BF16, EPI_FINAL };

__device__ __forceinline__ float wred_sum(float v) {
#pragma unroll
  for (int m = 1; m < 64; m <<= 1) v += __shfl_xor(v, m, 64);
  return v;
}

// bf16 MFMA GEMM body, 64x64 tile, double-buffered (16 KB within smem).
template <int EPI>
__device__ __forceinline__ void bgemm_body(char* smem, int bx, int by, int bz,
    const bf16* __restrict__ A, const bf16* __restrict__ B, void* __restrict__ C,
    int K, int ldC, long sA, long sB, long sC,
    const float* __restrict__ bias, const void* __restrict__ aux) {
  short (*Ahs)[2048] = (short(*)[2048])smem;
  short (*Bhs)[2048] = (short(*)[2048])(smem + 2 * 2048 * 2);
  const short* ah = (const short*)A + (long)bz * sA;
  const short* bh = (const short*)B + (long)bz * sB;
  int tid = threadIdx.x;
  int wv_ = tid >> 6, lane = tid & 63;
  int lrow = tid >> 2, lcol = (tid & 3) << 3;
  int lidx = lrow * 32 + lcol;
  long abase = (long)(bx * 64 + lrow) * K + lcol;
  long bbase = (long)(by * 64 + lrow) * K + lcol;
  int frow = lane & 15, fk = (lane >> 4) << 3;
  int aoff = (wv_ * 16 + frow) * 32 + fk;
  f4v acc[4] = {};
  {
    s8v avh = *(const s8v*)&ah[abase];
    s8v bvh = *(const s8v*)&bh[bbase];
    *(s8v*)&Ahs[0][lidx] = avh;
    *(s8v*)&Bhs[0][lidx] = bvh;
  }
  __syncthreads();
  int nit = K >> 5, buf = 0;
  for (int it = 0; it < nit; it++) {
    s8v avh, bvh;
    bool pf = (it + 1 < nit);
    if (pf) {
      long ko = (long)(it + 1) << 5;
      avh = *(const s8v*)&ah[abase + ko];
      bvh = *(const s8v*)&bh[bbase + ko];
    }
    s8v afh = *(const s8v*)&Ahs[buf][aoff];
#pragma unroll
    for (int nt = 0; nt < 4; nt++) {
      s8v bfh = *(const s8v*)&Bhs[buf][(nt * 16 + frow) * 32 + fk];
      acc[nt] = __builtin_amdgcn_mfma_f32_16x16x32_bf16(afh, bfh, acc[nt], 0, 0, 0);
    }
    if (pf) {
      *(s8v*)&Ahs[buf ^ 1][lidx] = avh;
      *(s8v*)&Bhs[buf ^ 1][lidx] = bvh;
      __syncthreads();
      buf ^= 1;
    }
  }
  int rb = bx * 64 + wv_ * 16 + ((lane >> 4) << 2);
#pragma unroll
  for (int nt = 0; nt < 4; nt++) {
    int gn = by * 64 + nt * 16 + (lane & 15);
#pragma unroll
    for (int rg = 0; rg < 4; rg++) {
      int gm = rb + rg;
      float v = acc[nt][rg];
      long ci = (long)bz * sC + (long)gm * ldC + gn;
      if (EPI == EPI_F32) ((float*)C)[ci] = v;
      else if (EPI == EPI_BIAS) ((float*)C)[ci] = v + bias[gn];
      else if (EPI == EPI_BRELU_BF16) ((bf16*)C)[ci] = __float2bfloat16(fmaxf(v + bias[gn], 0.f));
      else if (EPI == EPI_BF16) ((bf16*)C)[ci] = __float2bfloat16(v);
      else if (EPI == EPI_FINAL)
        ((float*)C)[ci] = v + bias[gm] + ((const float*)aux)[(long)gn * 512 + gm];
    }
  }
}

// ---------------------------------------------------------------------------
// f16x2 split-GEMM machinery (R13-R15): a*b reconstructed from hi/lo f16
// planes (lo pre-scaled by 2^12). 4 f16 MFMAs per fragment pair (hh -> acc0,
// hl+lh -> accx @2^-12, ll -> acc2 @2^-24); per-product error ~2^-22..2^-23
// ~= the reference's own f32 rounding.
// R15: SINGLE LDS buffer (20.5 KB -> 7 blocks/CU) + register prefetch +
// 2 barriers/iter (the R8-winner f64 loop shape) — attacks the latency-bound
// 8.5%-MfmaUtil profile of the double-buffered variant by ~1.75x TLP.
// LDS row stride 40 shorts (80B): 16B-aligned b128, <=2-way bank alias.
// ---------------------------------------------------------------------------

#define HX_DECL                                                     \
  short* L = (short*)smem;                                          \
  const int MS = 64 * 40;                                           \
  int tid = threadIdx.x;                                            \
  int wv = tid >> 6, lane = tid & 63;                               \
  int lrow = tid >> 2, lcol = (tid & 3) << 3;                       \
  int frow = lane & 15, fk = (lane >> 4) << 3;                      \
  int aoff = (wv * 16 + frow) * 40 + fk;                            \
  int soff = lrow * 40 + lcol;                                      \
  f4v acc0[4] = {}, accx[4] = {}, acc2[4] = {};

#define HX_STAGE0                                                   \
  {                                                                 \
    *(h8v*)&L[0 * MS + soff] = *(const h8v*)&Ah[abase];             \
    *(h8v*)&L[1 * MS + soff] = *(const h8v*)&Al[abase];             \
    *(h8v*)&L[2 * MS + soff] = *(const h8v*)&Bh[bbase];             \
    *(h8v*)&L[3 * MS + soff] = *(const h8v*)&Bl[bbase];             \
  }                                                                 \
  __syncthreads();

#define HX_LOOP(NIT)                                                \
  for (int it = 0; it < (NIT); it++) {                              \
    h8v pah, pal, pbh, pbl;                                         \
    bool pf = (it + 1 < (NIT));                                     \
    if (pf) {                                                       \
      long ko = (long)(it + 1) << 5;                                \
      pah = *(const h8v*)&Ah[abase + ko];                           \
      pal = *(const h8v*)&Al[abase + ko];                           \
      pbh = *(const h8v*)&Bh[bbase + ko];                           \
      pbl = *(const h8v*)&Bl[bbase + ko];                           \
    }                                                               \
    h8v ah = *(const h8v*)&L[aoff];                                 \
    h8v al = *(const h8v*)&L[MS + aoff];                            \
    _Pragma("unroll") for (int nt = 0; nt < 4; nt++) {              \
      int bo = 2 * MS + (nt * 16 + frow) * 40 + fk;                 \
      h8v bh = *(const h8v*)&L[bo];                                 \
      h8v bl = *(const h8v*)&L[bo + MS];                            \
      acc0[nt] = __builtin_amdgcn_mfma_f32_16x16x32_f16(ah, bh, acc0[nt], 0, 0, 0); \
      accx[nt] = __builtin_amdgcn_mfma_f32_16x16x32_f16(ah, bl, accx[nt], 0, 0, 0); \
      accx[nt] = __builtin_amdgcn_mfma_f32_16x16x32_f16(al, bh, accx[nt], 0, 0, 0); \
      acc2[nt] = __builtin_amdgcn_mfma_f32_16x16x32_f16(al, bl, acc2[nt], 0, 0, 0); \
    }                                                               \
    if (pf) {                                                       \
      __syncthreads();                                              \
      *(h8v*)&L[soff] = pah;                                        \
      *(h8v*)&L[MS + soff] = pal;                                   \
      *(h8v*)&L[2 * MS + soff] = pbh;                               \
      *(h8v*)&L[3 * MS + soff] = pbl;                               \
      __syncthreads();                                              \
    }                                                               \
  }

#define HX_COMBINE(nt, rg) \
  (acc0[nt][rg] + (accx[nt][rg] + acc2[nt][rg] * (1.f / 4096.f)) * (1.f / 4096.f))

// qk projection body with fused RoPE/repack epilogue.
// D layout (16x16x32 family): col=lane&15, row=(lane>>4)*4+rg.
__device__ __forceinline__ void qk_f16_body(char* smem, int bx, int by,
    const _Float16* __restrict__ Ah, const _Float16* __restrict__ Al,
    const _Float16* __restrict__ Bh, const _Float16* __restrict__ Bl,
    _Float16* __restrict__ qhh, _Float16* __restrict__ qhl,
    _Float16* __restrict__ kinh, _Float16* __restrict__ kinl,
    float* __restrict__ rq, float* __restrict__ rk, const float* __restrict__ kpos) {
  HX_DECL
  long abase = (long)(bx * 64 + lrow) * 512 + lcol;
  long bbase = (long)(by * 64 + lrow) * 512 + lcol;
  HX_STAGE0
  HX_LOOP(16)
  bool isq = by < 8;
  int h = by & 7;
  int rb = wv * 16 + ((lane >> 4) << 2);
#pragma unroll
  for (int nt = 0; nt < 4; nt++) {
    int dloc = nt * 16 + frow;
    int d2 = dloc >> 1;
    // 10000^(-2*d2/64) = exp2(-d2 * log2(10000)/32)
    float inv = exp2f((float)d2 * -0.4152410118609203f);
#pragma unroll
    for (int rg = 0; rg < 4; rg++) {
      int n = bx * 64 + rb + rg;
      float vf = HX_COMBINE(nt, rg);
      float ang = (float)n * inv;
      float sv, cv;
      sincosf(ang, &sv, &cv);
      float vp = __shfl_xor(vf, 1, 64);
      float rr = (dloc & 1) ? (vf * cv + vp * sv) : (vf * cv - vp * sv);
      long oi = ((long)h * 4096 + n) * 64 + dloc;
      if (isq) {
        _Float16 hi = (_Float16)vf;
        qhh[oi] = hi;
        qhl[oi] = (_Float16)((vf - (float)hi) * 4096.f);
        rq[oi] = rr;
      } else {
        rk[oi] = rr;
        float kv = vf + kpos[(h * 16 + (n & 15)) * 64 + dloc];
        _Float16 khi = (_Float16)kv;
        long ki = (((long)h * 256 + (n >> 4)) * 16 + (n & 15)) * 64 + dloc;
        kinh[ki] = khi;
        kinl[ki] = (_Float16)((kv - (float)khi) * 4096.f);
      }
    }
  }
}

// conv: xs = xt @ win^T + b_in, f32 out.
__device__ __forceinline__ void hx_conv_body(char* smem, int bx, int by,
    const _Float16* __restrict__ Ah, const _Float16* __restrict__ Al,
    const _Float16* __restrict__ Bh, const _Float16* __restrict__ Bl,
    float* __restrict__ C, const float* __restrict__ bias) {
  HX_DECL
  long abase = (long)(bx * 64 + lrow) * 512 + lcol;
  long bbase = (long)(by * 64 + lrow) * 512 + lcol;
  HX_STAGE0
  HX_LOOP(16)
  int rb = bx * 64 + wv * 16 + ((lane >> 4) << 2);
#pragma unroll
  for (int nt = 0; nt < 4; nt++) {
    int gn = by * 64 + nt * 16 + frow;
#pragma unroll
    for (int rg = 0; rg < 4; rg++) {
      int gm = rb + rg;
      C[(long)gm * 512 + gn] = HX_COMBINE(nt, rg) + bias[gn];
    }
  }
}

// K-MLP1: hid = relu(kin @ kw1^T + b1), output re-split into hi/lo planes.
__device__ __forceinline__ void hx_mlp1_body(char* smem, int bx, int by,
    const _Float16* __restrict__ Ah, const _Float16* __restrict__ Al,
    const _Float16* __restrict__ Bh, const _Float16* __restrict__ Bl,
    _Float16* __restrict__ Ch, _Float16* __restrict__ Cl, const float* __restrict__ bias) {
  HX_DECL
  long abase = (long)(bx * 64 + lrow) * 1024 + lcol;
  long bbase = (long)(by * 64 + lrow) * 1024 + lcol;
  HX_STAGE0
  HX_LOOP(32)
  int rb = bx * 64 + wv * 16 + ((lane >> 4) << 2);
#pragma unroll
  for (int nt = 0; nt < 4; nt++) {
    int gn = by * 64 + nt * 16 + frow;
#pragma unroll
    for (int rg = 0; rg < 4; rg++) {
      int gm = rb + rg;
      float v = fmaxf(HX_COMBINE(nt, rg) + bias[gn], 0.f);
      _Float16 hi = (_Float16)v;
      long ci = (long)gm * 1024 + gn;
      Ch[ci] = hi;
      Cl[ci] = (_Float16)((v - (float)hi) * 4096.f);
    }
  }
}

// K-MLP2 split-K (by = K-chunk of 128): f32 partials to P[by].
__device__ __forceinline__ void hx_ksplit_body(char* smem, int bx, int by,
    const _Float16* __restrict__ Ah, const _Float16* __restrict__ Al,
    const _Float16* __restrict__ Bh, const _Float16* __restrict__ Bl,
    float* __restrict__ P) {
  HX_DECL
  long kbeg = (long)by << 7;
  long abase = (long)(bx * 64 + lrow) * 1024 + kbeg + lcol;
  long bbase = (long)lrow * 1024 + kbeg + lcol;
  HX_STAGE0
  HX_LOOP(4)
  float* p = P + (long)by * 131072;
  int rb = bx * 64 + wv * 16 + ((lane >> 4) << 2);
#pragma unroll
  for (int nt = 0; nt < 4; nt++) {
    int gn = nt * 16 + frow;
#pragma unroll
    for (int rg = 0; rg < 4; rg++) {
      int gm = rb + rg;
      p[(long)gm * 64 + gn] = HX_COMBINE(nt, rg);
    }
  }
}

// csim = (qh @ ckb^T) * 0.125 per head bz; K=64 (2 iters).
__device__ __forceinline__ void hx_csim_body(char* smem, int bx, int by, int bz,
    const _Float16* __restrict__ Ah, const _Float16* __restrict__ Al,
    const _Float16* __restrict__ Bh, const _Float16* __restrict__ Bl,
    float* __restrict__ C) {
  HX_DECL
  long abase = ((long)bz * 4096 + bx * 64 + lrow) * 64 + lcol;
  long bbase = ((long)bz * 320 + by * 64 + lrow) * 64 + lcol;
  HX_STAGE0
  HX_LOOP(2)
  int rb = bx * 64 + wv * 16 + ((lane >> 4) << 2);
#pragma unroll
  for (int nt = 0; nt < 4; nt++) {
    int gn = by * 64 + nt * 16 + frow;
#pragma unroll
    for (int rg = 0; rg < 4; rg++) {
      int gm = rb + rg;
      C[((long)bz * 4096 + gm) * 320 + gn] = HX_COMBINE(nt, rg) * 0.125f;
    }
  }
}

// Weight-cast ladder (everything NOT needed by the conv GEMM itself).
__device__ __forceinline__ void prep_elem(long i,
    const float* __restrict__ wq, const float* __restrict__ wk, const float* __restrict__ wv,
    const float* __restrict__ wst, const float* __restrict__ bst,
    const float* __restrict__ kc_w1, const float* __restrict__ kc_w2,
    const float* __restrict__ vc_w1, const float* __restrict__ vc_w2, const float* __restrict__ w_comb,
    const float* __restrict__ w_out, _Float16* __restrict__ wqkh, _Float16* __restrict__ wqkl,
    bf16* __restrict__ wvs, float* __restrict__ bias2,
    _Float16* __restrict__ kw1h, _Float16* __restrict__ kw1l,
    _Float16* __restrict__ kw2h, _Float16* __restrict__ kw2l, bf16* __restrict__ vw1b,
    bf16* __restrict__ vw2b, bf16* __restrict__ wcombb, bf16* __restrict__ woutb) {
  if (i < 524288) {
    int r = (int)(i >> 9), c = (int)(i & 511);
    float w = (r < 512) ? wq[i] : wk[(r - 512) * 512 + c];
    _Float16 hi = (_Float16)w;
    wqkh[i] = hi;
    wqkl[i] = (_Float16)((w - (float)hi) * 4096.f);
    return;
  }
  i -= 524288;
  if (i < 294912) {
    int r = (int)(i >> 9), c = (int)(i & 511);
    float v = 0.f;
    if (r < 512) v = wv[i];
    else if (r < 536) v = wst[(r - 512) * 512 + c];
    wvs[i] = __float2bfloat16(v);
    if (i < 576) bias2[i] = (i >= 512 && i < 536) ? bst[i - 512] : 0.f;
    return;
  }
  i -= 294912;
  if (i < 1048576) {
    float w = kc_w1[i];
    _Float16 hi = (_Float16)w;
    kw1h[i] = hi;
    kw1l[i] = (_Float16)((w - (float)hi) * 4096.f);
    return;
  }
  i -= 1048576;
  if (i < 65536) {
    float w = kc_w2[i];
    _Float16 hi = (_Float16)w;
    kw2h[i] = hi;
    kw2l[i] = (_Float16)((w - (float)hi) * 4096.f);
    return;
  }
  i -= 65536;
  if (i < 1048576) { vw1b[i] = __float2bfloat16(vc_w1[i]); return; }
  i -= 1048576;
  if (i < 65536) { vw2b[i] = __float2bfloat16(vc_w2[i]); return; }
  i -= 65536;
  if (i < 262144) { wcombb[i] = __float2bfloat16(w_comb[i]); return; }
  i -= 262144;
  if (i < 262144) woutb[i] = __float2bfloat16(w_out[i]);
}
#define PREP_TOTAL 3571712l

// ---- standalone kernels ----
template <int EPI>
__global__ __launch_bounds__(256) void gemm_bt(
    const bf16* __restrict__ A, const bf16* __restrict__ B, void* __restrict__ C,
    int K, int ldC, long sA, long sB, long sC,
    const float* __restrict__ bias, const void* __restrict__ aux) {
  __shared__ char smem[4 * 2048 * 2];
  bgemm_body<EPI>(smem, blockIdx.x, blockIdx.y, blockIdx.z, A, B, C, K, ldC, sA, sB, sC, bias, aux);
}

// conv f16x2 GEMM (y<8) + weight-prep casts (y>=8) in one dispatch.
__global__ __launch_bounds__(256) void k_conv_prep(
    const _Float16* __restrict__ xth, const _Float16* __restrict__ xtl,
    const _Float16* __restrict__ winh, const _Float16* __restrict__ winl,
    float* __restrict__ xsf, const float* __restrict__ b_in,
    const float* __restrict__ wq, const float* __restrict__ wk, const float* __restrict__ wv,
    const float* __restrict__ wst, const float* __restrict__ bst,
    const float* __restrict__ kc_w1, const float* __restrict__ kc_w2,
    const float* __restrict__ vc_w1, const float* __restrict__ vc_w2, const float* __restrict__ w_comb,
    const float* __restrict__ w_out, _Float16* __restrict__ wqkh, _Float16* __restrict__ wqkl,
    bf16* __restrict__ wvs, float* __restrict__ bias2,
    _Float16* __restrict__ kw1h, _Float16* __restrict__ kw1l,
    _Float16* __restrict__ kw2h, _Float16* __restrict__ kw2l, bf16* __restrict__ vw1b,
    bf16* __restrict__ vw2b, bf16* __restrict__ wcombb, bf16* __restrict__ woutb) {
  __shared__ char smem[QSMEM];
  if (blockIdx.y < 8) {
    hx_conv_body(smem, blockIdx.x, blockIdx.y, xth, xtl, winh, winl, xsf, b_in);
  } else {
    long base = (((long)(blockIdx.y - 8) * 64 + blockIdx.x) * 256) + threadIdx.x;
    for (long i = base; i < PREP_TOTAL; i += 16l * 64 * 256)
      prep_elem(i, wq, wk, wv, wst, bst, kc_w1, kc_w2, vc_w1, vc_w2, w_comb, w_out,
                wqkh, wqkl, wvs, bias2, kw1h, kw1l, kw2h, kw2l, vw1b, vw2b, wcombb, woutb);
  }
}

// qk f16x2 split-GEMM (by<16) with FUSED repack epilogue. q-blocks (by<8):
// qh hi/lo planes + roped rq; k-blocks (by 8..15): roped rk + kin hi/lo.
// bf16 T2 GEMM at by>=16.
__global__ __launch_bounds__(256) void k_fused_qk_t2(
    const _Float16* __restrict__ hhi, const _Float16* __restrict__ hlo,
    const _Float16* __restrict__ wqkh, const _Float16* __restrict__ wqkl,
    _Float16* __restrict__ qhh, _Float16* __restrict__ qhl,
    _Float16* __restrict__ kinh, _Float16* __restrict__ kinl,
    float* __restrict__ rq, float* __restrict__ rk, const float* __restrict__ kpos,
    const bf16* __restrict__ hbf, const bf16* __restrict__ wvs, float* __restrict__ T2,
    const float* __restrict__ bias2) {
  __shared__ char smem[QSMEM];
  if (blockIdx.y >= 16) {
    bgemm_body<EPI_BIAS>(smem, blockIdx.x, blockIdx.y - 16, 0, hbf, wvs, T2, 512, 576, 0, 0, 0, bias2,
                         nullptr);
    return;
  }
  qk_f16_body(smem, blockIdx.x, blockIdx.y, hhi, hlo, wqkh, wqkl, qhh, qhl, kinh, kinl, rq, rk, kpos);
}

// slim v-repack: T2 v-part -> vvb (f32 head-major) + vin (bf16 + v_pos).
__global__ void k_repackV(const float* __restrict__ T2, const float* __restrict__ vpos,
                          float* __restrict__ vvv, bf16* __restrict__ vin) {
  int e = blockIdx.x * 256 + threadIdx.x;  // 8*4096*64
  int d = e & 63, n = (e >> 6) & 4095, h = e >> 18;
  float v0 = T2[(long)n * 576 + h * 64 + d];
  vvv[((long)h * 4096 + n) * 64 + d] = v0;
  vin[(((long)h * 256 + (n >> 4)) * 16 + (n & 15)) * 64 + d] =
      __float2bfloat16(v0 + vpos[(h * 16 + (n & 15)) * 64 + d]);
}

// K-MLP1 f16x2 (y<16) + V-MLP1 bf16 (y>=16).
__global__ __launch_bounds__(256) void k_fused_mlp1(
    const _Float16* __restrict__ kinh, const _Float16* __restrict__ kinl,
    const _Float16* __restrict__ kw1h, const _Float16* __restrict__ kw1l,
    _Float16* __restrict__ hidh, _Float16* __restrict__ hidl, const float* __restrict__ kb1,
    const bf16* __restrict__ vin, const bf16* __restrict__ vw1,
    bf16* __restrict__ hidv, const float* __restrict__ vb1) {
  __shared__ char smem[QSMEM];
  if (blockIdx.y < 16)
    hx_mlp1_body(smem, blockIdx.x, blockIdx.y, kinh, kinl, kw1h, kw1l, hidh, hidl, kb1);
  else
    bgemm_body<EPI_BRELU_BF16>(smem, blockIdx.x, blockIdx.y - 16, 0, vin, vw1, hidv, 1024, 1024, 0, 0, 0,
                               vb1, nullptr);
}

// K-MLP2 f16x2 split-K (y<8) + V-MLP2 bf16 (y==8).
__global__ __launch_bounds__(256) void k_fused_mlp2(
    const _Float16* __restrict__ hidh, const _Float16* __restrict__ hidl,
    const _Float16* __restrict__ kw2h, const _Float16* __restrict__ kw2l, float* __restrict__ kpart,
    const bf16* __restrict__ hidv, const bf16* __restrict__ vw2, float* __restrict__ cvc,
    const float* __restrict__ vb2) {
  __shared__ char smem[QSMEM];
  if (blockIdx.y < 8)
    hx_ksplit_body(smem, blockIdx.x, blockIdx.y, hidh, hidl, kw2h, kw2l, kpart);
  else
    bgemm_body<EPI_BIAS>(smem, blockIdx.x, 0, 0, hidv, vw2, cvc, 1024, 64, 0, 0, 0, vb2, nullptr);
}

// csim f16x2 GEMM: per head bz, 4096x320 @ K=64.
__global__ __launch_bounds__(256) void k_csim(
    const _Float16* __restrict__ qhh, const _Float16* __restrict__ qhl,
    const _Float16* __restrict__ ckbh, const _Float16* __restrict__ ckbl, float* __restrict__ csim) {
  __shared__ char smem[QSMEM];
  hx_csim_body(smem, blockIdx.x, blockIdx.y, blockIdx.z, qhh, qhl, ckbh, ckbl, csim);
}

// x (512,4096) f32 -> xt (4096,512) f16 hi/lo planes; y==16 slab casts win planes.
__global__ void k_transpose16(const float* __restrict__ x, _Float16* __restrict__ xth,
                              _Float16* __restrict__ xtl,
                              const float* __restrict__ w_in, _Float16* __restrict__ winh,
                              _Float16* __restrict__ winl) {
  if (blockIdx.y == 16) {
    int tid = threadIdx.y * 32 + threadIdx.x;
    long base = (long)blockIdx.x * 256 + tid;
    for (long i = base; i < 262144; i += 128l * 256) {
      float w = w_in[i];
      _Float16 hi = (_Float16)w;
      winh[i] = hi;
      winl[i] = (_Float16)((w - (float)hi) * 4096.f);
    }
    return;
  }
  __shared__ float t[32][33];
  int n0 = blockIdx.x * 32, c0 = blockIdx.y * 32;
  int tx = threadIdx.x, ty = threadIdx.y;
#pragma unroll
  for (int r = ty; r < 32; r += 8) t[r][tx] = x[(long)(c0 + r) * 4096 + n0 + tx];
  __syncthreads();
#pragma unroll
  for (int r = ty; r < 32; r += 8) {
    float v = t[tx][r];
    _Float16 hi = (_Float16)v;
    long o = (long)(n0 + r) * 512 + c0 + tx;
    xth[o] = hi;
    xtl[o] = (_Float16)((v - (float)hi) * 4096.f);
  }
}

// rmsnorm (f64 math on f32 xs) -> h f16 hi/lo planes + bf16 h.
__global__ __launch_bounds__(256) void k_rmsnorm(const float* __restrict__ xs, const float* __restrict__ g,
                                                 _Float16* __restrict__ hhi, _Float16* __restrict__ hlo,
                                                 bf16* __restrict__ hbf) {
  int n = blockIdx.x, t = threadIdx.x;
  const float* row = xs + (long)n * 512;
  double a = (double)row[t], b = (double)row[t + 256];
  double ss = a * a + b * b;
#pragma unroll
  for (int m = 1; m < 64; m <<= 1) ss += __shfl_xor(ss, m, 64);
  __shared__ double red[4];
  if ((t & 63) == 0) red[t >> 6] = ss;
  __syncthreads();
  double tot = red[0] + red[1] + red[2] + red[3];
  double r = 1.0 / sqrt(tot / 512.0 + 1e-6);
  double h0 = a * r * (double)g[t], h1 = b * r * (double)g[t + 256];
  long o = (long)n * 512 + t;
  float f0 = (float)h0, f1 = (float)h1;
  _Float16 a0 = (_Float16)f0, a1 = (_Float16)f1;
  hhi[o] = a0;
  hhi[o + 256] = a1;
  hlo[o] = (_Float16)((f0 - (float)a0) * 4096.f);
  hlo[o + 256] = (_Float16)((f1 - (float)a1) * 4096.f);
  hbf[o] = __float2bfloat16(f0);
  hbf[o + 256] = __float2bfloat16(f1);
}

// split-K f32 partials + cvc + mem rows -> ckb f16 planes (8,320,64), cvtb (8,64,288 bf16).
__global__ void k_repackB(const float* __restrict__ kpart, const float* __restrict__ cvc,
                          const float* __restrict__ mem_k, const float* __restrict__ mem_v,
                          const float* __restrict__ kb2, _Float16* __restrict__ ckbh,
                          _Float16* __restrict__ ckbl, bf16* __restrict__ cvtb) {
  int g = blockIdx.x * 256 + threadIdx.x;
  if (g < 8 * 320 * 64) {
    int d = g & 63, j = (g >> 6) % 320, h = g / (320 * 64);
    float vf = 0.f;
    if (j == 0) vf = mem_k[h * 64 + d];
    else if (j < 257) {
      long ri = ((long)h * 256 + (j - 1)) * 64 + d;
      double s = 0.0;
#pragma unroll
      for (int p = 0; p < 8; p++) s += (double)kpart[(long)p * 131072 + ri];
      vf = (float)(s + (double)kb2[d]);
    }
    _Float16 hi = (_Float16)vf;
    ckbh[g] = hi;
    ckbl[g] = (_Float16)((vf - (float)hi) * 4096.f);
  }
  if (g < 8 * 64 * 288) {
    int j = g % 288, d = (g / 288) & 63, h = g / (288 * 64);
    float v = 0.f;
    if (j == 0) v = mem_v[h * 64 + d];
    else if (j < 257) v = cvc[((long)h * 256 + (j - 1)) * 64 + d];
    cvtb[g] = __float2bfloat16(v);
  }
}

// Per (h,i) row: compressed softmax -> probs (bf16), and exact top-k block selection.
__global__ __launch_bounds__(256) void k_selsm(const float* __restrict__ csim, bf16* __restrict__ pb,
                                               int4* __restrict__ selb) {
  int r = blockIdx.x * 4 + (threadIdx.x >> 6);
  int lane = threadIdx.x & 63;
  int i = r & 4095;
  const float* row = csim + (long)r * 320;
  int nv = i / 16 + 1;
  float s[5], e[5];
  float mx = -INFINITY;
#pragma unroll
  for (int t = 0; t < 5; t++) {
    int j = lane + 64 * t;
    float v = (j < nv) ? row[j] : -INFINITY;
    s[t] = v;
    mx = fmaxf(mx, v);
  }
#pragma unroll
  for (int m = 1; m < 64; m <<= 1) mx = fmaxf(mx, __shfl_xor(mx, m, 64));
  float sum = 0.f;
#pragma unroll
  for (int t = 0; t < 5; t++) {
    int j = lane + 64 * t;
    e[t] = (j < nv) ? __expf(s[t] - mx) : 0.f;
    sum += e[t];
  }
  sum = wred_sum(sum);
  float rinv = 1.f / sum;
  bf16* prow = pb + (long)r * 288;
#pragma unroll
  for (int t = 0; t < 5; t++) {
    int j = lane + 64 * t;
    if (j < 288) prow[j] = __float2bfloat16((j < nv) ? e[t] * rinv : 0.f);
  }
  int nvb = i >> 1;
  int nmv = (nvb + 7) >> 3;
  float vm[4];
  float bestv = -INFINITY;
  int bestm = 0x7fffffff;
#pragma unroll
  for (int t = 0; t < 4; t++) {
    int m = lane + 64 * t;
    float v = -INFINITY;
    if (m < nmv) v = (m + 1 < nv) ? row[m + 1] : NEGF;
    vm[t] = v;
    if (v > bestv) { bestv = v; bestm = m; }
  }
#pragma unroll
  for (int mk = 1; mk < 64; mk <<= 1) {
    float ov = __shfl_xor(bestv, mk, 64);
    int om = __shfl_xor(bestm, mk, 64);
    if (ov > bestv || (ov == bestv && om < bestm)) { bestv = ov; bestm = om; }
  }
  int m0 = bestm;
  int cnt0 = min(8, nvb - 8 * m0);
  float rv = -INFINITY;
  int rm = 0x7fffffff;
#pragma unroll
  for (int t = 0; t < 4; t++) {
    int m = lane + 64 * t;
    if (m != m0 && vm[t] > rv) { rv = vm[t]; rm = m; }
  }
#pragma unroll
  for (int mk = 1; mk < 64; mk <<= 1) {
    float ov = __shfl_xor(rv, mk, 64);
    int om = __shfl_xor(rm, mk, 64);
    if (ov > rv || (ov == rv && om < rm)) { rv = ov; rm = om; }
  }
  float Ml = fmaxf(-1000.f, bestv);
  float z = 0.f;
#pragma unroll
  for (int t = 0; t < 4; t++) {
    int m = lane + 64 * t;
    if (m < nmv) z += (float)min(8, nvb - 8 * m) * expf(vm[t] - Ml);
  }
  z = wred_sum(z) + expf(-1000.f - Ml);
  int fb0 = 0, fb1 = 0, mk0 = 0, mk1 = 0;
  if (nmv > 0) {
    float sv0 = expf(bestv - Ml) / z;
    fb0 = 8 * m0;
    mk0 = sv0 > 1e-10f;
    if (cnt0 >= 2) { fb1 = fb0 + 1; mk1 = mk0; }
    else if (nmv > 1) {
      float sv1 = expf(rv - Ml) / z;
      fb1 = 8 * rm;
      mk1 = sv1 > 1e-10f;
    }
  }
  if (lane == 0) selb[r] = make_int4(fb0, fb1, mk0, mk1);
}

// Per (h,i): fine attention (selected + diag) + sliding window + gated combine.
__global__ __launch_bounds__(256) void k_fineslide(const float* __restrict__ rq, const float* __restrict__ rk,
                                                   const float* __restrict__ vv, const float* __restrict__ co,
                                                   const int4* __restrict__ selb, const float* __restrict__ T2,
                                                   bf16* __restrict__ comb) {
  int r = blockIdx.x * 4 + (threadIdx.x >> 6);
  int d = threadIdx.x & 63;
  int h = r >> 12, i = r & 4095;
  long hb = (long)h * 4096 * 64;
  float qd = rq[hb + (long)i * 64 + d];
  int4 s4 = selb[r];
  int dg = i >> 1;
  int tok[6] = {2 * s4.x, 2 * s4.x + 1, 2 * s4.y, 2 * s4.y + 1, 2 * dg, 2 * dg + 1};
  int ok6[6] = {s4.z, s4.z, s4.w, s4.w, 1, (i & 1)};
  float sim[6], val[6];
#pragma unroll
  for (int j = 0; j < 6; j++) {
    float kd = rk[hb + (long)tok[j] * 64 + d];
    val[j] = vv[hb + (long)tok[j] * 64 + d];
    float p = wred_sum(qd * kd);
    sim[j] = ok6[j] ? p * 0.125f : NEGF;
  }
  float mx = sim[0];
#pragma unroll
  for (int j = 1; j < 6; j++) mx = fmaxf(mx, sim[j]);
  float den = 0.f, fo = 0.f;
#pragma unroll
  for (int j = 0; j < 6; j++) {
    float e_ = __expf(sim[j] - mx);
    den += e_;
    fo += e_ * val[j];
  }
  fo /= den;
  float ssim[9], sval[9];
#pragma unroll
  for (int t = 0; t < 9; t++) {
    int tk = i - 8 + t;
    int okt = tk >= 0;
    int tc = okt ? tk : 0;
    float kd = rk[hb + (long)tc * 64 + d];
    sval[t] = okt ? vv[hb + (long)tc * 64 + d] : 0.f;
    float p = wred_sum(qd * kd);
    ssim[t] = okt ? p * 0.125f : NEGF;
  }
  float mx2 = ssim[8];
#pragma unroll
  for (int t = 0; t < 8; t++) mx2 = fmaxf(mx2, ssim[t]);
  float den2 = 0.f, so = 0.f;
#pragma unroll
  for (int t = 0; t < 9; t++) {
    float e_ = __expf(ssim[t] - mx2);
    den2 += e_;
    so += e_ * sval[t];
  }
  so /= den2;
  const float* gb = T2 + (long)i * 576 + 512 + h * 3;
  float g0 = 1.f / (1.f + __expf(-gb[0]));
  float g1 = 1.f / (1.f + __expf(-gb[1]));
  float g2 = 1.f / (1.f + __expf(-gb[2]));
  float cd = co[hb + (long)i * 64 + d];
  comb[(long)i * 512 + h * 64 + d] = __float2bfloat16(g0 * cd + g1 * fo + g2 * so);
}

extern "C" void kernel_launch(void* const* d_in, const int* in_sizes, int n_in, void* d_out, int out_size,
                              void* d_ws, size_t ws_size, hipStream_t stream) {
  (void)in_sizes; (void)n_in; (void)out_size; (void)ws_size;
  const float* x = (const float*)d_in[0];
  const float* w_in = (const float*)d_in[1];
  const float* b_in = (const float*)d_in[2];
  const float* g_norm = (const float*)d_in[3];
  const float* wq = (const float*)d_in[4];
  const float* wk = (const float*)d_in[5];
  const float* wv = (const float*)d_in[6];
  const float* k_pos = (const float*)d_in[7];
  const float* v_pos = (const float*)d_in[8];
  const float* mem_k = (const float*)d_in[9];
  const float* mem_v = (const float*)d_in[10];
  const float* kc_w1 = (const float*)d_in[11];
  const float* kc_b1 = (const float*)d_in[12];
  const float* kc_w2 = (const float*)d_in[13];
  const float* kc_b2 = (const float*)d_in[14];
  const float* vc_w1 = (const float*)d_in[15];
  const float* vc_b1 = (const float*)d_in[16];
  const float* vc_w2 = (const float*)d_in[17];
  const float* vc_b2 = (const float*)d_in[18];
  const float* w_strat = (const float*)d_in[19];
  const float* b_strat = (const float*)d_in[20];
  const float* w_comb = (const float*)d_in[21];
  const float* w_out = (const float*)d_in[22];
  const float* b_out = (const float*)d_in[23];

  char* wsp = (char*)d_ws;
  size_t off = 0;
  auto alloc = [&](size_t b) -> void* {
    void* p = wsp + off;
    off += (b + 255) & ~(size_t)255;
    return p;
  };
  float* xsf = (float*)alloc(4096l * 512 * 4);
  _Float16* hhi = (_Float16*)alloc(4096l * 512 * 2);
  _Float16* hlo = (_Float16*)alloc(4096l * 512 * 2);
  bf16* hbf = (bf16*)alloc(4096l * 512 * 2);
  _Float16* winh = (_Float16*)alloc(512l * 512 * 2);
  _Float16* winl = (_Float16*)alloc(512l * 512 * 2);
  _Float16* wqkh = (_Float16*)alloc(1024l * 512 * 2);
  _Float16* wqkl = (_Float16*)alloc(1024l * 512 * 2);
  bf16* wvs = (bf16*)alloc(576l * 512 * 2);
  float* bias2 = (float*)alloc(576 * 4);
  float* T2 = (float*)alloc(4096l * 576 * 4);
  float* csim = (float*)alloc(8l * 4096 * 320 * 4);
  _Float16* qhh = (_Float16*)alloc(8l * 4096 * 64 * 2);
  _Float16* qhl = (_Float16*)alloc(8l * 4096 * 64 * 2);
  float* rq = (float*)alloc(8l * 4096 * 64 * 4);
  float* rk = (float*)alloc(8l * 4096 * 64 * 4);
  float* vvb = (float*)alloc(8l * 4096 * 64 * 4);
  char* xthl = (char*)alloc(2l * 4096 * 512 * 2);  // xt planes, later hid planes
  _Float16* xth = (_Float16*)xthl;
  _Float16* xtl = xth + 4096l * 512;
  _Float16* hidh = xth;  // 2048*1024 == 4096*512 elems per plane
  _Float16* hidl = xtl;
  char* kinpb = (char*)alloc(2048l * 1024 * 8 + 2048l * 1024 * 2);  // kin planes + vin, later pb
  _Float16* kinh = (_Float16*)kinpb;
  _Float16* kinl = kinh + 2048l * 1024;
  bf16* vinb = (bf16*)(kinpb + 2l * 2048 * 1024 * 2);
  bf16* pb = (bf16*)kinpb;
  _Float16* kw1h = (_Float16*)alloc(1024l * 1024 * 2);
  _Float16* kw1l = (_Float16*)alloc(1024l * 1024 * 2);
  _Float16* kw2h = (_Float16*)alloc(64l * 1024 * 2);
  _Float16* kw2l = (_Float16*)alloc(64l * 1024 * 2);
  bf16* vw1b = (bf16*)alloc(1024l * 1024 * 2);
  bf16* vw2b = (bf16*)alloc(64l * 1024 * 2);
  bf16* hidv = (bf16*)alloc(2048l * 1024 * 2);
  float* cvc = (float*)alloc(2048l * 64 * 4);
  _Float16* ckbh = (_Float16*)alloc(8l * 320 * 64 * 2);
  _Float16* ckbl = (_Float16*)alloc(8l * 320 * 64 * 2);
  bf16* cvtb = (bf16*)alloc(8l * 64 * 288 * 2);
  int4* selb = (int4*)alloc(32768l * 16);
  float* co = (float*)alloc(8l * 4096 * 64 * 4);
  bf16* comb = (bf16*)alloc(4096l * 512 * 2);
  bf16* zb = (bf16*)alloc(4096l * 512 * 2);
  bf16* wcombb = (bf16*)alloc(512l * 512 * 2);
  bf16* woutb = (bf16*)alloc(512l * 512 * 2);
  float* kpart = (float*)alloc(8l * 2048 * 64 * 4);  // split-K f32 partials

  // ---- transpose to f16 planes + conv-weight plane cast ----
  k_transpose16<<<dim3(128, 17), dim3(32, 8), 0, stream>>>(x, xth, xtl, w_in, winh, winl);
  // ---- conv (f16x2) + all remaining weight prep in one dispatch ----
  k_conv_prep<<<dim3(64, 24), 256, 0, stream>>>(xth, xtl, winh, winl, xsf, b_in, wq, wk, wv, w_strat,
                                                b_strat, kc_w1, kc_w2, vc_w1, vc_w2, w_comb, w_out,
                                                wqkh, wqkl, wvs, bias2, kw1h, kw1l, kw2h, kw2l,
                                                vw1b, vw2b, wcombb, woutb);
  k_rmsnorm<<<4096, 256, 0, stream>>>(xsf, g_norm, hhi, hlo, hbf);
  // ---- qk f16x2 GEMM with fused repack epilogue (+ T2 bf16 GEMM) ----
  k_fused_qk_t2<<<dim3(64, 25, 1), 256, 0, stream>>>(hhi, hlo, wqkh, wqkl, qhh, qhl, kinh, kinl, rq, rk,
                                                     k_pos, hbf, wvs, T2, bias2);
  k_repackV<<<8192, 256, 0, stream>>>(T2, v_pos, vvb, vinb);
  k_fused_mlp1<<<dim3(32, 32, 1), 256, 0, stream>>>(kinh, kinl, kw1h, kw1l, hidh, hidl, kc_b1, vinb, vw1b,
                                                    hidv, vc_b1);
  k_fused_mlp2<<<dim3(32, 9, 1), 256, 0, stream>>>(hidh, hidl, kw2h, kw2l, kpart, hidv, vw2b, cvc, vc_b2);
  k_repackB<<<640, 256, 0, stream>>>(kpart, cvc, mem_k, mem_v, kc_b2, ckbh, ckbl, cvtb);
  k_csim<<<dim3(64, 5, 8), 256, 0, stream>>>(qhh, qhl, ckbh, ckbl, csim);
  // ---- selection + attention combine (standalone fineslide, full TLP) ----
  k_selsm<<<8192, 256, 0, stream>>>(csim, pb, selb);
  gemm_bt<EPI_F32><<<dim3(64, 1, 8), 256, 0, stream>>>(pb, cvtb, co, 288, 64, 4096l * 288, 64l * 288,
                                                       4096l * 64, nullptr, nullptr);
  k_fineslide<<<8192, 256, 0, stream>>>(rq, rk, vvb, co, selb, T2, comb);
  // ---- output mixing ----
  gemm_bt<EPI_BF16><<<dim3(64, 8, 1), 256, 0, stream>>>(comb, wcombb, zb, 512, 512, 0, 0, 0, nullptr, nullptr);
  gemm_bt<EPI_FINAL><<<dim3(8, 64, 1), 256, 0, stream>>>(woutb, zb, d_out, 512, 4096, 0, 0, 0, b_out, xsf);
}

// Round 4
// 325.643 us; speedup vs baseline: 1.5029x; 1.0179x over previous
//
#include <hip/hip_runtime.h>
#include <hip/hip_bf16.h>
#include <math.h>

typedef __attribute__((ext_vector_type(8))) short s8v;
typedef __attribute__((ext_vector_type(8))) _Float16 h8v;
typedef __attribute__((ext_vector_type(4))) float f4v;
typedef __hip_bfloat16 bf16;

#define NEGF (-3.40282346638528859812e+38f)
#define QSMEM 20480  // f16x2 single-buffer: 4 mats x 64 rows x 40 shorts x 2B
#define BSMEM 20480  // bf16 double-buffer: 2 bufs x 2 mats x 64 x 40 shorts x 2B

enum { EPI_F32 = 0, EPI_BIAS, EPI_BRELU_BF16, EPI_BF16, EPI_FINAL };

__device__ __forceinline__ float wred_sum(float v) {
#pragma unroll
  for (int m = 1; m < 64; m <<= 1) v += __shfl_xor(v, m, 64);
  return v;
}

// ---------------------------------------------------------------------------
// bf16 MFMA GEMM body, 64x64 tile, double-buffered, stride-40 LDS rows
// (R16: was stride 32 = 8-way bank conflict on the B fragment reads), with
// 2-deep register prefetch (alternating reg sets, no copies — a reg copy
// would force the vmcnt wait one iteration early).
// ---------------------------------------------------------------------------
template <int EPI>
__device__ __forceinline__ void bgemm_body(char* smem, int bx, int by, int bz,
    const bf16* __restrict__ A, const bf16* __restrict__ B, void* __restrict__ C,
    int K, int ldC, long sA, long sB, long sC,
    const float* __restrict__ bias, const void* __restrict__ aux) {
  short (*Ahs)[2560] = (short(*)[2560])smem;
  short (*Bhs)[2560] = (short(*)[2560])(smem + 2 * 2560 * 2);
  const short* ah = (const short*)A + (long)bz * sA;
  const short* bh = (const short*)B + (long)bz * sB;
  int tid = threadIdx.x;
  int wv_ = tid >> 6, lane = tid & 63;
  int lrow = tid >> 2, lcol = (tid & 3) << 3;
  int lidx = lrow * 40 + lcol;
  long abase = (long)(bx * 64 + lrow) * K + lcol;
  long bbase = (long)(by * 64 + lrow) * K + lcol;
  int frow = lane & 15, fk = (lane >> 4) << 3;
  int aoff = (wv_ * 16 + frow) * 40 + fk;
  f4v acc[4] = {};
  {
    s8v avh = *(const s8v*)&ah[abase];
    s8v bvh = *(const s8v*)&bh[bbase];
    *(s8v*)&Ahs[0][lidx] = avh;
    *(s8v*)&Bhs[0][lidx] = bvh;
  }
  __syncthreads();
  int nit = K >> 5, buf = 0;
  s8v rAa, rAb, rBa, rBb;
  if (nit > 1) {
    rAa = *(const s8v*)&ah[abase + 32];
    rAb = *(const s8v*)&bh[bbase + 32];
  }
#define B_DSMFMA                                                       \
  {                                                                    \
    s8v afh = *(const s8v*)&Ahs[buf][aoff];                            \
    _Pragma("unroll") for (int nt = 0; nt < 4; nt++) {                 \
      s8v bfh = *(const s8v*)&Bhs[buf][(nt * 16 + frow) * 40 + fk];    \
      acc[nt] = __builtin_amdgcn_mfma_f32_16x16x32_bf16(afh, bfh, acc[nt], 0, 0, 0); \
    }                                                                  \
  }
  for (int it = 0; it < nit; it += 2) {
    if (it + 2 < nit) {
      long ko = (long)(it + 2) << 5;
      rBa = *(const s8v*)&ah[abase + ko];
      rBb = *(const s8v*)&bh[bbase + ko];
    }
    B_DSMFMA
    if (it + 1 < nit) {
      *(s8v*)&Ahs[buf ^ 1][lidx] = rAa;
      *(s8v*)&Bhs[buf ^ 1][lidx] = rAb;
      __syncthreads();
      buf ^= 1;
      if (it + 3 < nit) {
        long ko = (long)(it + 3) << 5;
        rAa = *(const s8v*)&ah[abase + ko];
        rAb = *(const s8v*)&bh[bbase + ko];
      }
      B_DSMFMA
      if (it + 2 < nit) {
        *(s8v*)&Ahs[buf ^ 1][lidx] = rBa;
        *(s8v*)&Bhs[buf ^ 1][lidx] = rBb;
        __syncthreads();
        buf ^= 1;
      }
    }
  }
#undef B_DSMFMA
  int rb = bx * 64 + wv_ * 16 + ((lane >> 4) << 2);
#pragma unroll
  for (int nt = 0; nt < 4; nt++) {
    int gn = by * 64 + nt * 16 + (lane & 15);
#pragma unroll
    for (int rg = 0; rg < 4; rg++) {
      int gm = rb + rg;
      float v = acc[nt][rg];
      long ci = (long)bz * sC + (long)gm * ldC + gn;
      if (EPI == EPI_F32) ((float*)C)[ci] = v;
      else if (EPI == EPI_BIAS) ((float*)C)[ci] = v + bias[gn];
      else if (EPI == EPI_BRELU_BF16) ((bf16*)C)[ci] = __float2bfloat16(fmaxf(v + bias[gn], 0.f));
      else if (EPI == EPI_BF16) ((bf16*)C)[ci] = __float2bfloat16(v);
      else if (EPI == EPI_FINAL)
        ((float*)C)[ci] = v + bias[gm] + ((const float*)aux)[(long)gn * 512 + gm];
    }
  }
}

// ---------------------------------------------------------------------------
// f16x2 split-GEMM machinery (R13-R16): a*b reconstructed from hi/lo f16
// planes (lo pre-scaled by 2^12). 4 f16 MFMAs per fragment pair; per-product
// error ~2^-22..2^-23 ~= the reference's own f32 rounding.
// R15: single LDS buffer + reg prefetch, 2 barriers/iter.
// R16: 2-deep register prefetch (alternating sets rA/rB, manual 2x unroll) so
// global loads stay in flight ~1.5-2 iters (~600-1000 cyc >= L2/HBM latency).
// LDS row stride 40 shorts (80B): 16B-aligned b128, <=2-way bank alias.
// ---------------------------------------------------------------------------

#define HX_DECL                                                     \
  short* L = (short*)smem;                                          \
  const int MS = 64 * 40;                                           \
  int tid = threadIdx.x;                                            \
  int wv = tid >> 6, lane = tid & 63;                               \
  int lrow = tid >> 2, lcol = (tid & 3) << 3;                       \
  int frow = lane & 15, fk = (lane >> 4) << 3;                      \
  int aoff = (wv * 16 + frow) * 40 + fk;                            \
  int soff = lrow * 40 + lcol;                                      \
  f4v acc0[4] = {}, accx[4] = {}, acc2[4] = {};

#define HX_STAGE0                                                   \
  {                                                                 \
    *(h8v*)&L[0 * MS + soff] = *(const h8v*)&Ah[abase];             \
    *(h8v*)&L[1 * MS + soff] = *(const h8v*)&Al[abase];             \
    *(h8v*)&L[2 * MS + soff] = *(const h8v*)&Bh[bbase];             \
    *(h8v*)&L[3 * MS + soff] = *(const h8v*)&Bl[bbase];             \
  }                                                                 \
  __syncthreads();

#define HX_DSMFMA                                                   \
  {                                                                 \
    h8v ah = *(const h8v*)&L[aoff];                                 \
    h8v al = *(const h8v*)&L[MS + aoff];                            \
    _Pragma("unroll") for (int nt = 0; nt < 4; nt++) {              \
      int bo = 2 * MS + (nt * 16 + frow) * 40 + fk;                 \
      h8v bh = *(const h8v*)&L[bo];                                 \
      h8v bl = *(const h8v*)&L[bo + MS];                            \
      acc0[nt] = __builtin_amdgcn_mfma_f32_16x16x32_f16(ah, bh, acc0[nt], 0, 0, 0); \
      accx[nt] = __builtin_amdgcn_mfma_f32_16x16x32_f16(ah, bl, accx[nt], 0, 0, 0); \
      accx[nt] = __builtin_amdgcn_mfma_f32_16x16x32_f16(al, bh, accx[nt], 0, 0, 0); \
      acc2[nt] = __builtin_amdgcn_mfma_f32_16x16x32_f16(al, bl, acc2[nt], 0, 0, 0); \
    }                                                               \
  }

#define HX_LOOP(NIT)                                                \
  h8v rAa, rAb, rAc, rAd, rBa, rBb, rBc, rBd;                       \
  if ((NIT) > 1) {                                                  \
    rAa = *(const h8v*)&Ah[abase + 32];                             \
    rAb = *(const h8v*)&Al[abase + 32];                             \
    rAc = *(const h8v*)&Bh[bbase + 32];                             \
    rAd = *(const h8v*)&Bl[bbase + 32];                             \
  }                                                                 \
  for (int it = 0; it < (NIT); it += 2) {                           \
    if (it + 2 < (NIT)) {                                           \
      long ko = (long)(it + 2) << 5;                                \
      rBa = *(const h8v*)&Ah[abase + ko];                           \
      rBb = *(const h8v*)&Al[abase + ko];                           \
      rBc = *(const h8v*)&Bh[bbase + ko];                           \
      rBd = *(const h8v*)&Bl[bbase + ko];                           \
    }                                                               \
    HX_DSMFMA                                                       \
    if (it + 1 < (NIT)) {                                           \
      __syncthreads();                                              \
      *(h8v*)&L[soff] = rAa;                                        \
      *(h8v*)&L[MS + soff] = rAb;                                   \
      *(h8v*)&L[2 * MS + soff] = rAc;                               \
      *(h8v*)&L[3 * MS + soff] = rAd;                               \
      __syncthreads();                                              \
      if (it + 3 < (NIT)) {                                         \
        long ko = (long)(it + 3) << 5;                              \
        rAa = *(const h8v*)&Ah[abase + ko];                         \
        rAb = *(const h8v*)&Al[abase + ko];                         \
        rAc = *(const h8v*)&Bh[bbase + ko];                         \
        rAd = *(const h8v*)&Bl[bbase + ko];                         \
      }                                                             \
      HX_DSMFMA                                                     \
      if (it + 2 < (NIT)) {                                         \
        __syncthreads();                                            \
        *(h8v*)&L[soff] = rBa;                                      \
        *(h8v*)&L[MS + soff] = rBb;                                 \
        *(h8v*)&L[2 * MS + soff] = rBc;                             \
        *(h8v*)&L[3 * MS + soff] = rBd;                             \
        __syncthreads();                                            \
      }                                                             \
    }                                                               \
  }

#define HX_COMBINE(nt, rg) \
  (acc0[nt][rg] + (accx[nt][rg] + acc2[nt][rg] * (1.f / 4096.f)) * (1.f / 4096.f))

// qk projection body with fused RoPE/repack epilogue. RoPE sin/cos from a
// precomputed table (bit-identical values; removes 16 sincosf/thread).
// D layout (16x16x32 family): col=lane&15, row=(lane>>4)*4+rg.
__device__ __forceinline__ void qk_f16_body(char* smem, int bx, int by,
    const _Float16* __restrict__ Ah, const _Float16* __restrict__ Al,
    const _Float16* __restrict__ Bh, const _Float16* __restrict__ Bl,
    _Float16* __restrict__ qhh, _Float16* __restrict__ qhl,
    _Float16* __restrict__ kinh, _Float16* __restrict__ kinl,
    float* __restrict__ rq, float* __restrict__ rk, const float* __restrict__ kpos,
    const float2* __restrict__ ropet) {
  HX_DECL
  long abase = (long)(bx * 64 + lrow) * 512 + lcol;
  long bbase = (long)(by * 64 + lrow) * 512 + lcol;
  HX_STAGE0
  HX_LOOP(16)
  bool isq = by < 8;
  int h = by & 7;
  int rb = wv * 16 + ((lane >> 4) << 2);
#pragma unroll
  for (int nt = 0; nt < 4; nt++) {
    int dloc = nt * 16 + frow;
    int d2 = dloc >> 1;
#pragma unroll
    for (int rg = 0; rg < 4; rg++) {
      int n = bx * 64 + rb + rg;
      float vf = HX_COMBINE(nt, rg);
      float2 cs = ropet[(long)n * 32 + d2];
      float sv = cs.x, cv = cs.y;
      float vp = __shfl_xor(vf, 1, 64);
      float rr = (dloc & 1) ? (vf * cv + vp * sv) : (vf * cv - vp * sv);
      long oi = ((long)h * 4096 + n) * 64 + dloc;
      if (isq) {
        _Float16 hi = (_Float16)vf;
        qhh[oi] = hi;
        qhl[oi] = (_Float16)((vf - (float)hi) * 4096.f);
        rq[oi] = rr;
      } else {
        rk[oi] = rr;
        float kv = vf + kpos[(h * 16 + (n & 15)) * 64 + dloc];
        _Float16 khi = (_Float16)kv;
        long ki = (((long)h * 256 + (n >> 4)) * 16 + (n & 15)) * 64 + dloc;
        kinh[ki] = khi;
        kinl[ki] = (_Float16)((kv - (float)khi) * 4096.f);
      }
    }
  }
}

// conv: xs = xt @ win^T + b_in, f32 out.
__device__ __forceinline__ void hx_conv_body(char* smem, int bx, int by,
    const _Float16* __restrict__ Ah, const _Float16* __restrict__ Al,
    const _Float16* __restrict__ Bh, const _Float16* __restrict__ Bl,
    float* __restrict__ C, const float* __restrict__ bias) {
  HX_DECL
  long abase = (long)(bx * 64 + lrow) * 512 + lcol;
  long bbase = (long)(by * 64 + lrow) * 512 + lcol;
  HX_STAGE0
  HX_LOOP(16)
  int rb = bx * 64 + wv * 16 + ((lane >> 4) << 2);
#pragma unroll
  for (int nt = 0; nt < 4; nt++) {
    int gn = by * 64 + nt * 16 + frow;
#pragma unroll
    for (int rg = 0; rg < 4; rg++) {
      int gm = rb + rg;
      C[(long)gm * 512 + gn] = HX_COMBINE(nt, rg) + bias[gn];
    }
  }
}

// K-MLP1: hid = relu(kin @ kw1^T + b1), output re-split into hi/lo planes.
__device__ __forceinline__ void hx_mlp1_body(char* smem, int bx, int by,
    const _Float16* __restrict__ Ah, const _Float16* __restrict__ Al,
    const _Float16* __restrict__ Bh, const _Float16* __restrict__ Bl,
    _Float16* __restrict__ Ch, _Float16* __restrict__ Cl, const float* __restrict__ bias) {
  HX_DECL
  long abase = (long)(bx * 64 + lrow) * 1024 + lcol;
  long bbase = (long)(by * 64 + lrow) * 1024 + lcol;
  HX_STAGE0
  HX_LOOP(32)
  int rb = bx * 64 + wv * 16 + ((lane >> 4) << 2);
#pragma unroll
  for (int nt = 0; nt < 4; nt++) {
    int gn = by * 64 + nt * 16 + frow;
#pragma unroll
    for (int rg = 0; rg < 4; rg++) {
      int gm = rb + rg;
      float v = fmaxf(HX_COMBINE(nt, rg) + bias[gn], 0.f);
      _Float16 hi = (_Float16)v;
      long ci = (long)gm * 1024 + gn;
      Ch[ci] = hi;
      Cl[ci] = (_Float16)((v - (float)hi) * 4096.f);
    }
  }
}

// K-MLP2 split-K (by = K-chunk of 128): f32 partials to P[by].
__device__ __forceinline__ void hx_ksplit_body(char* smem, int bx, int by,
    const _Float16* __restrict__ Ah, const _Float16* __restrict__ Al,
    const _Float16* __restrict__ Bh, const _Float16* __restrict__ Bl,
    float* __restrict__ P) {
  HX_DECL
  long kbeg = (long)by << 7;
  long abase = (long)(bx * 64 + lrow) * 1024 + kbeg + lcol;
  long bbase = (long)lrow * 1024 + kbeg + lcol;
  HX_STAGE0
  HX_LOOP(4)
  float* p = P + (long)by * 131072;
  int rb = bx * 64 + wv * 16 + ((lane >> 4) << 2);
#pragma unroll
  for (int nt = 0; nt < 4; nt++) {
    int gn = nt * 16 + frow;
#pragma unroll
    for (int rg = 0; rg < 4; rg++) {
      int gm = rb + rg;
      p[(long)gm * 64 + gn] = HX_COMBINE(nt, rg);
    }
  }
}

// csim = (qh @ ckb^T) * 0.125 per head bz; K=64 (2 iters).
__device__ __forceinline__ void hx_csim_body(char* smem, int bx, int by, int bz,
    const _Float16* __restrict__ Ah, const _Float16* __restrict__ Al,
    const _Float16* __restrict__ Bh, const _Float16* __restrict__ Bl,
    float* __restrict__ C) {
  HX_DECL
  long abase = ((long)bz * 4096 + bx * 64 + lrow) * 64 + lcol;
  long bbase = ((long)bz * 320 + by * 64 + lrow) * 64 + lcol;
  HX_STAGE0
  HX_LOOP(2)
  int rb = bx * 64 + wv * 16 + ((lane >> 4) << 2);
#pragma unroll
  for (int nt = 0; nt < 4; nt++) {
    int gn = by * 64 + nt * 16 + frow;
#pragma unroll
    for (int rg = 0; rg < 4; rg++) {
      int gm = rb + rg;
      C[((long)bz * 4096 + gm) * 320 + gn] = HX_COMBINE(nt, rg) * 0.125f;
    }
  }
}

// Weight-cast ladder (everything NOT needed by the conv GEMM itself).
__device__ __forceinline__ void prep_elem(long i,
    const float* __restrict__ wq, const float* __restrict__ wk, const float* __restrict__ wv,
    const float* __restrict__ wst, const float* __restrict__ bst,
    const float* __restrict__ kc_w1, const float* __restrict__ kc_w2,
    const float* __restrict__ vc_w1, const float* __restrict__ vc_w2, const float* __restrict__ w_comb,
    const float* __restrict__ w_out, _Float16* __restrict__ wqkh, _Float16* __restrict__ wqkl,
    bf16* __restrict__ wvs, float* __restrict__ bias2,
    _Float16* __restrict__ kw1h, _Float16* __restrict__ kw1l,
    _Float16* __restrict__ kw2h, _Float16* __restrict__ kw2l, bf16* __restrict__ vw1b,
    bf16* __restrict__ vw2b, bf16* __restrict__ wcombb, bf16* __restrict__ woutb) {
  if (i < 524288) {
    int r = (int)(i >> 9), c = (int)(i & 511);
    float w = (r < 512) ? wq[i] : wk[(r - 512) * 512 + c];
    _Float16 hi = (_Float16)w;
    wqkh[i] = hi;
    wqkl[i] = (_Float16)((w - (float)hi) * 4096.f);
    return;
  }
  i -= 524288;
  if (i < 294912) {
    int r = (int)(i >> 9), c = (int)(i & 511);
    float v = 0.f;
    if (r < 512) v = wv[i];
    else if (r < 536) v = wst[(r - 512) * 512 + c];
    wvs[i] = __float2bfloat16(v);
    if (i < 576) bias2[i] = (i >= 512 && i < 536) ? bst[i - 512] : 0.f;
    return;
  }
  i -= 294912;
  if (i < 1048576) {
    float w = kc_w1[i];
    _Float16 hi = (_Float16)w;
    kw1h[i] = hi;
    kw1l[i] = (_Float16)((w - (float)hi) * 4096.f);
    return;
  }
  i -= 1048576;
  if (i < 65536) {
    float w = kc_w2[i];
    _Float16 hi = (_Float16)w;
    kw2h[i] = hi;
    kw2l[i] = (_Float16)((w - (float)hi) * 4096.f);
    return;
  }
  i -= 65536;
  if (i < 1048576) { vw1b[i] = __float2bfloat16(vc_w1[i]); return; }
  i -= 1048576;
  if (i < 65536) { vw2b[i] = __float2bfloat16(vc_w2[i]); return; }
  i -= 65536;
  if (i < 262144) { wcombb[i] = __float2bfloat16(w_comb[i]); return; }
  i -= 262144;
  if (i < 262144) woutb[i] = __float2bfloat16(w_out[i]);
}
#define PREP_TOTAL 3571712l

// ---- standalone kernels ----
template <int EPI>
__global__ __launch_bounds__(256) void gemm_bt(
    const bf16* __restrict__ A, const bf16* __restrict__ B, void* __restrict__ C,
    int K, int ldC, long sA, long sB, long sC,
    const float* __restrict__ bias, const void* __restrict__ aux) {
  __shared__ char smem[BSMEM];
  bgemm_body<EPI>(smem, blockIdx.x, blockIdx.y, blockIdx.z, A, B, C, K, ldC, sA, sB, sC, bias, aux);
}

// conv f16x2 GEMM (y<8) + weight-prep casts (y>=8) in one dispatch.
__global__ __launch_bounds__(256) void k_conv_prep(
    const _Float16* __restrict__ xth, const _Float16* __restrict__ xtl,
    const _Float16* __restrict__ winh, const _Float16* __restrict__ winl,
    float* __restrict__ xsf, const float* __restrict__ b_in,
    const float* __restrict__ wq, const float* __restrict__ wk, const float* __restrict__ wv,
    const float* __restrict__ wst, const float* __restrict__ bst,
    const float* __restrict__ kc_w1, const float* __restrict__ kc_w2,
    const float* __restrict__ vc_w1, const float* __restrict__ vc_w2, const float* __restrict__ w_comb,
    const float* __restrict__ w_out, _Float16* __restrict__ wqkh, _Float16* __restrict__ wqkl,
    bf16* __restrict__ wvs, float* __restrict__ bias2,
    _Float16* __restrict__ kw1h, _Float16* __restrict__ kw1l,
    _Float16* __restrict__ kw2h, _Float16* __restrict__ kw2l, bf16* __restrict__ vw1b,
    bf16* __restrict__ vw2b, bf16* __restrict__ wcombb, bf16* __restrict__ woutb) {
  __shared__ char smem[QSMEM];
  if (blockIdx.y < 8) {
    hx_conv_body(smem, blockIdx.x, blockIdx.y, xth, xtl, winh, winl, xsf, b_in);
  } else {
    long base = (((long)(blockIdx.y - 8) * 64 + blockIdx.x) * 256) + threadIdx.x;
    for (long i = base; i < PREP_TOTAL; i += 16l * 64 * 256)
      prep_elem(i, wq, wk, wv, wst, bst, kc_w1, kc_w2, vc_w1, vc_w2, w_comb, w_out,
                wqkh, wqkl, wvs, bias2, kw1h, kw1l, kw2h, kw2l, vw1b, vw2b, wcombb, woutb);
  }
}

// qk f16x2 split-GEMM (by<16) with FUSED repack epilogue. q-blocks (by<8):
// qh hi/lo planes + roped rq; k-blocks (by 8..15): roped rk + kin hi/lo.
// bf16 T2 GEMM at by>=16.
__global__ __launch_bounds__(256) void k_fused_qk_t2(
    const _Float16* __restrict__ hhi, const _Float16* __restrict__ hlo,
    const _Float16* __restrict__ wqkh, const _Float16* __restrict__ wqkl,
    _Float16* __restrict__ qhh, _Float16* __restrict__ qhl,
    _Float16* __restrict__ kinh, _Float16* __restrict__ kinl,
    float* __restrict__ rq, float* __restrict__ rk, const float* __restrict__ kpos,
    const float2* __restrict__ ropet,
    const bf16* __restrict__ hbf, const bf16* __restrict__ wvs, float* __restrict__ T2,
    const float* __restrict__ bias2) {
  __shared__ char smem[QSMEM];
  if (blockIdx.y >= 16) {
    bgemm_body<EPI_BIAS>(smem, blockIdx.x, blockIdx.y - 16, 0, hbf, wvs, T2, 512, 576, 0, 0, 0, bias2,
                         nullptr);
    return;
  }
  qk_f16_body(smem, blockIdx.x, blockIdx.y, hhi, hlo, wqkh, wqkl, qhh, qhl, kinh, kinl, rq, rk, kpos,
              ropet);
}

// slim v-repack: T2 v-part -> vvb (f32 head-major) + vin (bf16 + v_pos).
__global__ void k_repackV(const float* __restrict__ T2, const float* __restrict__ vpos,
                          float* __restrict__ vvv, bf16* __restrict__ vin) {
  int e = blockIdx.x * 256 + threadIdx.x;  // 8*4096*64
  int d = e & 63, n = (e >> 6) & 4095, h = e >> 18;
  float v0 = T2[(long)n * 576 + h * 64 + d];
  vvv[((long)h * 4096 + n) * 64 + d] = v0;
  vin[(((long)h * 256 + (n >> 4)) * 16 + (n & 15)) * 64 + d] =
      __float2bfloat16(v0 + vpos[(h * 16 + (n & 15)) * 64 + d]);
}

// K-MLP1 f16x2 (y<16) + V-MLP1 bf16 (y>=16).
__global__ __launch_bounds__(256) void k_fused_mlp1(
    const _Float16* __restrict__ kinh, const _Float16* __restrict__ kinl,
    const _Float16* __restrict__ kw1h, const _Float16* __restrict__ kw1l,
    _Float16* __restrict__ hidh, _Float16* __restrict__ hidl, const float* __restrict__ kb1,
    const bf16* __restrict__ vin, const bf16* __restrict__ vw1,
    bf16* __restrict__ hidv, const float* __restrict__ vb1) {
  __shared__ char smem[QSMEM];
  if (blockIdx.y < 16)
    hx_mlp1_body(smem, blockIdx.x, blockIdx.y, kinh, kinl, kw1h, kw1l, hidh, hidl, kb1);
  else
    bgemm_body<EPI_BRELU_BF16>(smem, blockIdx.x, blockIdx.y - 16, 0, vin, vw1, hidv, 1024, 1024, 0, 0, 0,
                               vb1, nullptr);
}

// K-MLP2 f16x2 split-K (y<8) + V-MLP2 bf16 (y==8).
__global__ __launch_bounds__(256) void k_fused_mlp2(
    const _Float16* __restrict__ hidh, const _Float16* __restrict__ hidl,
    const _Float16* __restrict__ kw2h, const _Float16* __restrict__ kw2l, float* __restrict__ kpart,
    const bf16* __restrict__ hidv, const bf16* __restrict__ vw2, float* __restrict__ cvc,
    const float* __restrict__ vb2) {
  __shared__ char smem[QSMEM];
  if (blockIdx.y < 8)
    hx_ksplit_body(smem, blockIdx.x, blockIdx.y, hidh, hidl, kw2h, kw2l, kpart);
  else
    bgemm_body<EPI_BIAS>(smem, blockIdx.x, 0, 0, hidv, vw2, cvc, 1024, 64, 0, 0, 0, vb2, nullptr);
}

// csim f16x2 GEMM: per head bz, 4096x320 @ K=64. Causal-dead tiles skipped:
// rows in tile bx only ever read cols j <= bx*4+3 (selsm guards j < nv).
__global__ __launch_bounds__(256) void k_csim(
    const _Float16* __restrict__ qhh, const _Float16* __restrict__ qhl,
    const _Float16* __restrict__ ckbh, const _Float16* __restrict__ ckbl, float* __restrict__ csim) {
  if (blockIdx.y * 64 > blockIdx.x * 4 + 3) return;
  __shared__ char smem[QSMEM];
  hx_csim_body(smem, blockIdx.x, blockIdx.y, blockIdx.z, qhh, qhl, ckbh, ckbl, csim);
}

// x (512,4096) f32 -> xt (4096,512) f16 hi/lo planes; y==16 slab casts win
// planes + builds the 4096x32 RoPE (sin,cos) table.
__global__ void k_transpose16(const float* __restrict__ x, _Float16* __restrict__ xth,
                              _Float16* __restrict__ xtl,
                              const float* __restrict__ w_in, _Float16* __restrict__ winh,
                              _Float16* __restrict__ winl, float2* __restrict__ ropet) {
  if (blockIdx.y == 16) {
    int tid = threadIdx.y * 32 + threadIdx.x;
    long base = (long)blockIdx.x * 256 + tid;
    for (long i = base; i < 393216; i += 128l * 256) {
      if (i < 262144) {
        float w = w_in[i];
        _Float16 hi = (_Float16)w;
        winh[i] = hi;
        winl[i] = (_Float16)((w - (float)hi) * 4096.f);
      } else {
        int idx = (int)(i - 262144);
        int d2 = idx & 31, n = idx >> 5;
        float inv = exp2f((float)d2 * -0.4152410118609203f);
        float sv, cv;
        sincosf((float)n * inv, &sv, &cv);
        ropet[idx] = make_float2(sv, cv);
      }
    }
    return;
  }
  __shared__ float t[32][33];
  int n0 = blockIdx.x * 32, c0 = blockIdx.y * 32;
  int tx = threadIdx.x, ty = threadIdx.y;
#pragma unroll
  for (int r = ty; r < 32; r += 8) t[r][tx] = x[(long)(c0 + r) * 4096 + n0 + tx];
  __syncthreads();
#pragma unroll
  for (int r = ty; r < 32; r += 8) {
    float v = t[tx][r];
    _Float16 hi = (_Float16)v;
    long o = (long)(n0 + r) * 512 + c0 + tx;
    xth[o] = hi;
    xtl[o] = (_Float16)((v - (float)hi) * 4096.f);
  }
}

// rmsnorm (f64 math on f32 xs) -> h f16 hi/lo planes + bf16 h.
__global__ __launch_bounds__(256) void k_rmsnorm(const float* __restrict__ xs, const float* __restrict__ g,
                                                 _Float16* __restrict__ hhi, _Float16* __restrict__ hlo,
                                                 bf16* __restrict__ hbf) {
  int n = blockIdx.x, t = threadIdx.x;
  const float* row = xs + (long)n * 512;
  double a = (double)row[t], b = (double)row[t + 256];
  double ss = a * a + b * b;
#pragma unroll
  for (int m = 1; m < 64; m <<= 1) ss += __shfl_xor(ss, m, 64);
  __shared__ double red[4];
  if ((t & 63) == 0) red[t >> 6] = ss;
  __syncthreads();
  double tot = red[0] + red[1] + red[2] + red[3];
  double r = 1.0 / sqrt(tot / 512.0 + 1e-6);
  double h0 = a * r * (double)g[t], h1 = b * r * (double)g[t + 256];
  long o = (long)n * 512 + t;
  float f0 = (float)h0, f1 = (float)h1;
  _Float16 a0 = (_Float16)f0, a1 = (_Float16)f1;
  hhi[o] = a0;
  hhi[o + 256] = a1;
  hlo[o] = (_Float16)((f0 - (float)a0) * 4096.f);
  hlo[o + 256] = (_Float16)((f1 - (float)a1) * 4096.f);
  hbf[o] = __float2bfloat16(f0);
  hbf[o + 256] = __float2bfloat16(f1);
}

// split-K f32 partials + cvc + mem rows -> ckb f16 planes (8,320,64), cvtb (8,64,288 bf16).
__global__ void k_repackB(const float* __restrict__ kpart, const float* __restrict__ cvc,
                          const float* __restrict__ mem_k, const float* __restrict__ mem_v,
                          const float* __restrict__ kb2, _Float16* __restrict__ ckbh,
                          _Float16* __restrict__ ckbl, bf16* __restrict__ cvtb) {
  int g = blockIdx.x * 256 + threadIdx.x;
  if (g < 8 * 320 * 64) {
    int d = g & 63, j = (g >> 6) % 320, h = g / (320 * 64);
    float vf = 0.f;
    if (j == 0) vf = mem_k[h * 64 + d];
    else if (j < 257) {
      long ri = ((long)h * 256 + (j - 1)) * 64 + d;
      double s = 0.0;
#pragma unroll
      for (int p = 0; p < 8; p++) s += (double)kpart[(long)p * 131072 + ri];
      vf = (float)(s + (double)kb2[d]);
    }
    _Float16 hi = (_Float16)vf;
    ckbh[g] = hi;
    ckbl[g] = (_Float16)((vf - (float)hi) * 4096.f);
  }
  if (g < 8 * 64 * 288) {
    int j = g % 288, d = (g / 288) & 63, h = g / (288 * 64);
    float v = 0.f;
    if (j == 0) v = mem_v[h * 64 + d];
    else if (j < 257) v = cvc[((long)h * 256 + (j - 1)) * 64 + d];
    cvtb[g] = __float2bfloat16(v);
  }
}

// Per (h,i) row: compressed softmax -> probs (bf16), and exact top-k block selection.
__global__ __launch_bounds__(256) void k_selsm(const float* __restrict__ csim, bf16* __restrict__ pb,
                                               int4* __restrict__ selb) {
  int r = blockIdx.x * 4 + (threadIdx.x >> 6);
  int lane = threadIdx.x & 63;
  int i = r & 4095;
  const float* row = csim + (long)r * 320;
  int nv = i / 16 + 1;
  float s[5], e[5];
  float mx = -INFINITY;
#pragma unroll
  for (int t = 0; t < 5; t++) {
    int j = lane + 64 * t;
    float v = (j < nv) ? row[j] : -INFINITY;
    s[t] = v;
    mx = fmaxf(mx, v);
  }
#pragma unroll
  for (int m = 1; m < 64; m <<= 1) mx = fmaxf(mx, __shfl_xor(mx, m, 64));
  float sum = 0.f;
#pragma unroll
  for (int t = 0; t < 5; t++) {
    int j = lane + 64 * t;
    e[t] = (j < nv) ? __expf(s[t] - mx) : 0.f;
    sum += e[t];
  }
  sum = wred_sum(sum);
  float rinv = 1.f / sum;
  bf16* prow = pb + (long)r * 288;
#pragma unroll
  for (int t = 0; t < 5; t++) {
    int j = lane + 64 * t;
    if (j < 288) prow[j] = __float2bfloat16((j < nv) ? e[t] * rinv : 0.f);
  }
  int nvb = i >> 1;
  int nmv = (nvb + 7) >> 3;
  float vm[4];
  float bestv = -INFINITY;
  int bestm = 0x7fffffff;
#pragma unroll
  for (int t = 0; t < 4; t++) {
    int m = lane + 64 * t;
    float v = -INFINITY;
    if (m < nmv) v = (m + 1 < nv) ? row[m + 1] : NEGF;
    vm[t] = v;
    if (v > bestv) { bestv = v; bestm = m; }
  }
#pragma unroll
  for (int mk = 1; mk < 64; mk <<= 1) {
    float ov = __shfl_xor(bestv, mk, 64);
    int om = __shfl_xor(bestm, mk, 64);
    if (ov > bestv || (ov == bestv && om < bestm)) { bestv = ov; bestm = om; }
  }
  int m0 = bestm;
  int cnt0 = min(8, nvb - 8 * m0);
  float rv = -INFINITY;
  int rm = 0x7fffffff;
#pragma unroll
  for (int t = 0; t < 4; t++) {
    int m = lane + 64 * t;
    if (m != m0 && vm[t] > rv) { rv = vm[t]; rm = m; }
  }
#pragma unroll
  for (int mk = 1; mk < 64; mk <<= 1) {
    float ov = __shfl_xor(rv, mk, 64);
    int om = __shfl_xor(rm, mk, 64);
    if (ov > rv || (ov == rv && om < rm)) { rv = ov; rm = om; }
  }
  float Ml = fmaxf(-1000.f, bestv);
  float z = 0.f;
#pragma unroll
  for (int t = 0; t < 4; t++) {
    int m = lane + 64 * t;
    if (m < nmv) z += (float)min(8, nvb - 8 * m) * expf(vm[t] - Ml);
  }
  z = wred_sum(z) + expf(-1000.f - Ml);
  int fb0 = 0, fb1 = 0, mk0 = 0, mk1 = 0;
  if (nmv > 0) {
    float sv0 = expf(bestv - Ml) / z;
    fb0 = 8 * m0;
    mk0 = sv0 > 1e-10f;
    if (cnt0 >= 2) { fb1 = fb0 + 1; mk1 = mk0; }
    else if (nmv > 1) {
      float sv1 = expf(rv - Ml) / z;
      fb1 = 8 * rm;
      mk1 = sv1 > 1e-10f;
    }
  }
  if (lane == 0) selb[r] = make_int4(fb0, fb1, mk0, mk1);
}

// Per (h,i): fine attention (selected + diag) + sliding window + gated combine.
__global__ __launch_bounds__(256) void k_fineslide(const float* __restrict__ rq, const float* __restrict__ rk,
                                                   const float* __restrict__ vv, const float* __restrict__ co,
                                                   const int4* __restrict__ selb, const float* __restrict__ T2,
                                                   bf16* __restrict__ comb) {
  int r = blockIdx.x * 4 + (threadIdx.x >> 6);
  int d = threadIdx.x & 63;
  int h = r >> 12, i = r & 4095;
  long hb = (long)h * 4096 * 64;
  float qd = rq[hb + (long)i * 64 + d];
  int4 s4 = selb[r];
  int dg = i >> 1;
  int tok[6] = {2 * s4.x, 2 * s4.x + 1, 2 * s4.y, 2 * s4.y + 1, 2 * dg, 2 * dg + 1};
  int ok6[6] = {s4.z, s4.z, s4.w, s4.w, 1, (i & 1)};
  float sim[6], val[6];
#pragma unroll
  for (int j = 0; j < 6; j++) {
    float kd = rk[hb + (long)tok[j] * 64 + d];
    val[j] = vv[hb + (long)tok[j] * 64 + d];
    float p = wred_sum(qd * kd);
    sim[j] = ok6[j] ? p * 0.125f : NEGF;
  }
  float mx = sim[0];
#pragma unroll
  for (int j = 1; j < 6; j++) mx = fmaxf(mx, sim[j]);
  float den = 0.f, fo = 0.f;
#pragma unroll
  for (int j = 0; j < 6; j++) {
    float e_ = __expf(sim[j] - mx);
    den += e_;
    fo += e_ * val[j];
  }
  fo /= den;
  float ssim[9], sval[9];
#pragma unroll
  for (int t = 0; t < 9; t++) {
    int tk = i - 8 + t;
    int okt = tk >= 0;
    int tc = okt ? tk : 0;
    float kd = rk[hb + (long)tc * 64 + d];
    sval[t] = okt ? vv[hb + (long)tc * 64 + d] : 0.f;
    float p = wred_sum(qd * kd);
    ssim[t] = okt ? p * 0.125f : NEGF;
  }
  float mx2 = ssim[8];
#pragma unroll
  for (int t = 0; t < 8; t++) mx2 = fmaxf(mx2, ssim[t]);
  float den2 = 0.f, so = 0.f;
#pragma unroll
  for (int t = 0; t < 9; t++) {
    float e_ = __expf(ssim[t] - mx2);
    den2 += e_;
    so += e_ * sval[t];
  }
  so /= den2;
  const float* gb = T2 + (long)i * 576 + 512 + h * 3;
  float g0 = 1.f / (1.f + __expf(-gb[0]));
  float g1 = 1.f / (1.f + __expf(-gb[1]));
  float g2 = 1.f / (1.f + __expf(-gb[2]));
  float cd = co[hb + (long)i * 64 + d];
  comb[(long)i * 512 + h * 64 + d] = __float2bfloat16(g0 * cd + g1 * fo + g2 * so);
}

extern "C" void kernel_launch(void* const* d_in, const int* in_sizes, int n_in, void* d_out, int out_size,
                              void* d_ws, size_t ws_size, hipStream_t stream) {
  (void)in_sizes; (void)n_in; (void)out_size; (void)ws_size;
  const float* x = (const float*)d_in[0];
  const float* w_in = (const float*)d_in[1];
  const float* b_in = (const float*)d_in[2];
  const float* g_norm = (const float*)d_in[3];
  const float* wq = (const float*)d_in[4];
  const float* wk = (const float*)d_in[5];
  const float* wv = (const float*)d_in[6];
  const float* k_pos = (const float*)d_in[7];
  const float* v_pos = (const float*)d_in[8];
  const float* mem_k = (const float*)d_in[9];
  const float* mem_v = (const float*)d_in[10];
  const float* kc_w1 = (const float*)d_in[11];
  const float* kc_b1 = (const float*)d_in[12];
  const float* kc_w2 = (const float*)d_in[13];
  const float* kc_b2 = (const float*)d_in[14];
  const float* vc_w1 = (const float*)d_in[15];
  const float* vc_b1 = (const float*)d_in[16];
  const float* vc_w2 = (const float*)d_in[17];
  const float* vc_b2 = (const float*)d_in[18];
  const float* w_strat = (const float*)d_in[19];
  const float* b_strat = (const float*)d_in[20];
  const float* w_comb = (const float*)d_in[21];
  const float* w_out = (const float*)d_in[22];
  const float* b_out = (const float*)d_in[23];

  char* wsp = (char*)d_ws;
  size_t off = 0;
  auto alloc = [&](size_t b) -> void* {
    void* p = wsp + off;
    off += (b + 255) & ~(size_t)255;
    return p;
  };
  float* xsf = (float*)alloc(4096l * 512 * 4);
  _Float16* hhi = (_Float16*)alloc(4096l * 512 * 2);
  _Float16* hlo = (_Float16*)alloc(4096l * 512 * 2);
  bf16* hbf = (bf16*)alloc(4096l * 512 * 2);
  _Float16* winh = (_Float16*)alloc(512l * 512 * 2);
  _Float16* winl = (_Float16*)alloc(512l * 512 * 2);
  _Float16* wqkh = (_Float16*)alloc(1024l * 512 * 2);
  _Float16* wqkl = (_Float16*)alloc(1024l * 512 * 2);
  bf16* wvs = (bf16*)alloc(576l * 512 * 2);
  float* bias2 = (float*)alloc(576 * 4);
  float2* ropet = (float2*)alloc(4096l * 32 * 8);
  float* T2 = (float*)alloc(4096l * 576 * 4);
  float* csim = (float*)alloc(8l * 4096 * 320 * 4);
  _Float16* qhh = (_Float16*)alloc(8l * 4096 * 64 * 2);
  _Float16* qhl = (_Float16*)alloc(8l * 4096 * 64 * 2);
  float* rq = (float*)alloc(8l * 4096 * 64 * 4);
  float* rk = (float*)alloc(8l * 4096 * 64 * 4);
  float* vvb = (float*)alloc(8l * 4096 * 64 * 4);
  char* xthl = (char*)alloc(2l * 4096 * 512 * 2);  // xt planes, later hid planes
  _Float16* xth = (_Float16*)xthl;
  _Float16* xtl = xth + 4096l * 512;
  _Float16* hidh = xth;  // 2048*1024 == 4096*512 elems per plane
  _Float16* hidl = xtl;
  char* kinpb = (char*)alloc(2048l * 1024 * 8 + 2048l * 1024 * 2);  // kin planes + vin, later pb
  _Float16* kinh = (_Float16*)kinpb;
  _Float16* kinl = kinh + 2048l * 1024;
  bf16* vinb = (bf16*)(kinpb + 2l * 2048 * 1024 * 2);
  bf16* pb = (bf16*)kinpb;
  _Float16* kw1h = (_Float16*)alloc(1024l * 1024 * 2);
  _Float16* kw1l = (_Float16*)alloc(1024l * 1024 * 2);
  _Float16* kw2h = (_Float16*)alloc(64l * 1024 * 2);
  _Float16* kw2l = (_Float16*)alloc(64l * 1024 * 2);
  bf16* vw1b = (bf16*)alloc(1024l * 1024 * 2);
  bf16* vw2b = (bf16*)alloc(64l * 1024 * 2);
  bf16* hidv = (bf16*)alloc(2048l * 1024 * 2);
  float* cvc = (float*)alloc(2048l * 64 * 4);
  _Float16* ckbh = (_Float16*)alloc(8l * 320 * 64 * 2);
  _Float16* ckbl = (_Float16*)alloc(8l * 320 * 64 * 2);
  bf16* cvtb = (bf16*)alloc(8l * 64 * 288 * 2);
  int4* selb = (int4*)alloc(32768l * 16);
  float* co = (float*)alloc(8l * 4096 * 64 * 4);
  bf16* comb = (bf16*)alloc(4096l * 512 * 2);
  bf16* zb = (bf16*)alloc(4096l * 512 * 2);
  bf16* wcombb = (bf16*)alloc(512l * 512 * 2);
  bf16* woutb = (bf16*)alloc(512l * 512 * 2);
  float* kpart = (float*)alloc(8l * 2048 * 64 * 4);  // split-K f32 partials

  // ---- transpose to f16 planes + conv-weight plane cast + RoPE table ----
  k_transpose16<<<dim3(128, 17), dim3(32, 8), 0, stream>>>(x, xth, xtl, w_in, winh, winl, ropet);
  // ---- conv (f16x2) + all remaining weight prep in one dispatch ----
  k_conv_prep<<<dim3(64, 24), 256, 0, stream>>>(xth, xtl, winh, winl, xsf, b_in, wq, wk, wv, w_strat,
                                                b_strat, kc_w1, kc_w2, vc_w1, vc_w2, w_comb, w_out,
                                                wqkh, wqkl, wvs, bias2, kw1h, kw1l, kw2h, kw2l,
                                                vw1b, vw2b, wcombb, woutb);
  k_rmsnorm<<<4096, 256, 0, stream>>>(xsf, g_norm, hhi, hlo, hbf);
  // ---- qk f16x2 GEMM with fused repack epilogue (+ T2 bf16 GEMM) ----
  k_fused_qk_t2<<<dim3(64, 25, 1), 256, 0, stream>>>(hhi, hlo, wqkh, wqkl, qhh, qhl, kinh, kinl, rq, rk,
                                                     k_pos, ropet, hbf, wvs, T2, bias2);
  k_repackV<<<8192, 256, 0, stream>>>(T2, v_pos, vvb, vinb);
  k_fused_mlp1<<<dim3(32, 32, 1), 256, 0, stream>>>(kinh, kinl, kw1h, kw1l, hidh, hidl, kc_b1, vinb, vw1b,
                                                    hidv, vc_b1);
  k_fused_mlp2<<<dim3(32, 9, 1), 256, 0, stream>>>(hidh, hidl, kw2h, kw2l, kpart, hidv, vw2b, cvc, vc_b2);
  k_repackB<<<640, 256, 0, stream>>>(kpart, cvc, mem_k, mem_v, kc_b2, ckbh, ckbl, cvtb);
  k_csim<<<dim3(64, 5, 8), 256, 0, stream>>>(qhh, qhl, ckbh, ckbl, csim);
  // ---- selection + attention combine (standalone fineslide, full TLP) ----
  k_selsm<<<8192, 256, 0, stream>>>(csim, pb, selb);
  gemm_bt<EPI_F32><<<dim3(64, 1, 8), 256, 0, stream>>>(pb, cvtb, co, 288, 64, 4096l * 288, 64l * 288,
                                                       4096l * 64, nullptr, nullptr);
  k_fineslide<<<8192, 256, 0, stream>>>(rq, rk, vvb, co, selb, T2, comb);
  // ---- output mixing ----
  gemm_bt<EPI_BF16><<<dim3(64, 8, 1), 256, 0, stream>>>(comb, wcombb, zb, 512, 512, 0, 0, 0, nullptr, nullptr);
  gemm_bt<EPI_FINAL><<<dim3(8, 64, 1), 256, 0, stream>>>(woutb, zb, d_out, 512, 4096, 0, 0, 0, b_out, xsf);
}